// Round 1
// baseline (1186.666 us; speedup 1.0000x reference)
//
#include <hip/hip_runtime.h>
#include <math.h>

#define Bc 16
#define Nc 1024
#define Fc 256
#define Hc 8
#define Kc 512
#define DOUTc 256
#define EPSc 1e-8f
#define ROWS 16

__device__ __forceinline__ float waveReduceSum(float v) {
    v += __shfl_xor(v, 32); v += __shfl_xor(v, 16); v += __shfl_xor(v, 8);
    v += __shfl_xor(v, 4);  v += __shfl_xor(v, 2);  v += __shfl_xor(v, 1);
    return v;
}
__device__ __forceinline__ float waveReduceMax(float v) {
    v = fmaxf(v, __shfl_xor(v, 32)); v = fmaxf(v, __shfl_xor(v, 16));
    v = fmaxf(v, __shfl_xor(v, 8));  v = fmaxf(v, __shfl_xor(v, 4));
    v = fmaxf(v, __shfl_xor(v, 2));  v = fmaxf(v, __shfl_xor(v, 1));
    return v;
}

// ---------------- kernel 0: k2[h*K+k] = sum_f keys^2 ----------------
__global__ __launch_bounds__(256) void k2_kernel(const float* __restrict__ keys,
                                                 float* __restrict__ k2g) {
    int c = blockIdx.x * 256 + threadIdx.x;  // 0..4095
    const float4* kp = (const float4*)(keys + (size_t)c * Fc);
    float s = 0.f;
#pragma unroll 8
    for (int i = 0; i < Fc / 4; i++) {
        float4 v = kp[i];
        s += v.x * v.x + v.y * v.y + v.z * v.z + v.w * v.w;
    }
    k2g[c] = s;
}

// ---------------- kernel 1: C[b,n,k] (distance -> cauchy -> norm -> head-mix -> softmax -> mask)
__global__ __launch_bounds__(256) void compute_C_kernel(
    const float* __restrict__ Q, const float* __restrict__ keys,
    const float* __restrict__ conv_w, const int* __restrict__ mask,
    const float* __restrict__ k2g, float* __restrict__ C) {
    __shared__ float qs[ROWS][Fc + 4];
    __shared__ float redbuf[4][ROWS];
    __shared__ float q2s[ROWS];
    __shared__ float msh[ROWS];
    __shared__ float wsh[Hc];

    const int tid = threadIdx.x;
    const int b = blockIdx.x / (Nc / ROWS);
    const int n0 = (blockIdx.x % (Nc / ROWS)) * ROWS;

    // stage Q rows (16 x 256) into LDS, coalesced float4
    for (int i = tid; i < ROWS * (Fc / 4); i += 256) {
        int r = i >> 6, f4 = i & 63;
        float4 v = *(const float4*)(Q + ((size_t)(b * Nc + n0 + r)) * Fc + f4 * 4);
        *(float4*)&qs[r][f4 * 4] = v;
    }
    if (tid < Hc) wsh[tid] = conv_w[tid];
    if (tid < ROWS) msh[tid] = (float)mask[b * Nc + n0 + tid];
    __syncthreads();

    // q2 per row: 16 lanes per row
    {
        int r = tid >> 4, l = tid & 15;
        float p = 0.f;
        for (int f = l; f < Fc; f += 16) { float v = qs[r][f]; p += v * v; }
        p += __shfl_xor(p, 8, 16); p += __shfl_xor(p, 4, 16);
        p += __shfl_xor(p, 2, 16); p += __shfl_xor(p, 1, 16);
        if (l == 0) q2s[r] = p;
    }
    __syncthreads();

    float S0[ROWS], S1[ROWS];
#pragma unroll
    for (int r = 0; r < ROWS; r++) { S0[r] = 0.f; S1[r] = 0.f; }

    for (int h = 0; h < Hc; h++) {
        const int ca = h * Kc + tid;       // this thread's two key columns
        const int cb = ca + 256;
        const float4* kpa = (const float4*)(keys + (size_t)ca * Fc);
        const float4* kpb = (const float4*)(keys + (size_t)cb * Fc);
        float acc0[ROWS], acc1[ROWS];
#pragma unroll
        for (int r = 0; r < ROWS; r++) { acc0[r] = 0.f; acc1[r] = 0.f; }
        for (int f4 = 0; f4 < Fc / 4; f4++) {
            float4 ka = kpa[f4];
            float4 kb = kpb[f4];
#pragma unroll
            for (int r = 0; r < ROWS; r++) {
                float4 qv = *(const float4*)&qs[r][f4 * 4];
                acc0[r] += qv.x * ka.x + qv.y * ka.y + qv.z * ka.z + qv.w * ka.w;
                acc1[r] += qv.x * kb.x + qv.y * kb.y + qv.z * kb.z + qv.w * kb.w;
            }
        }
        float k2a = k2g[ca], k2b = k2g[cb];
        float ta[ROWS], tb[ROWS];
#pragma unroll
        for (int r = 0; r < ROWS; r++) {
            float m = msh[r];
            float d2a = fmaxf(q2s[r] + k2a - 2.f * acc0[r], 0.f) * m;
            float d2b = fmaxf(q2s[r] + k2b - 2.f * acc1[r], 0.f) * m;
            // (1 + d^2/TAU)^(-(0.5*TAU+0.5)) with TAU=1 -> 1/(1+d^2)
            ta[r] = 1.f / (1.f + d2a);
            tb[r] = 1.f / (1.f + d2b);
        }
        // block-wide per-row sums over the 512 keys of this head
#pragma unroll
        for (int r = 0; r < ROWS; r++) {
            float v = waveReduceSum(ta[r] + tb[r]);
            if ((tid & 63) == 0) redbuf[tid >> 6][r] = v;
        }
        __syncthreads();
        float wh = wsh[h];
#pragma unroll
        for (int r = 0; r < ROWS; r++) {
            float rs = redbuf[0][r] + redbuf[1][r] + redbuf[2][r] + redbuf[3][r];
            float sc = wh / rs;
            // note: masked rows get garbage S, but final C is multiplied by mask -> 0 either way
            S0[r] += ta[r] * sc;
            S1[r] += tb[r] * sc;
        }
        __syncthreads();
    }

    // softmax over k (512 values, 2 per thread per row)
    float mx[ROWS];
#pragma unroll
    for (int r = 0; r < ROWS; r++) {
        float v = waveReduceMax(fmaxf(S0[r], S1[r]));
        if ((tid & 63) == 0) redbuf[tid >> 6][r] = v;
    }
    __syncthreads();
#pragma unroll
    for (int r = 0; r < ROWS; r++)
        mx[r] = fmaxf(fmaxf(redbuf[0][r], redbuf[1][r]), fmaxf(redbuf[2][r], redbuf[3][r]));
    __syncthreads();
    float e0[ROWS], e1[ROWS];
#pragma unroll
    for (int r = 0; r < ROWS; r++) {
        e0[r] = expf(S0[r] - mx[r]);
        e1[r] = expf(S1[r] - mx[r]);
        float v = waveReduceSum(e0[r] + e1[r]);
        if ((tid & 63) == 0) redbuf[tid >> 6][r] = v;
    }
    __syncthreads();
#pragma unroll
    for (int r = 0; r < ROWS; r++) {
        float denom = redbuf[0][r] + redbuf[1][r] + redbuf[2][r] + redbuf[3][r];
        float inv = msh[r] / denom;
        size_t base = ((size_t)(b * Nc + n0 + r)) * Kc;
        C[base + tid] = e0[r] * inv;
        C[base + 256 + tid] = e1[r] * inv;
    }
}

// ---------------- kernel 2: cn[b,k] = sum_n C[b,n,k] ----------------
__global__ __launch_bounds__(256) void cn_kernel(const float* __restrict__ C,
                                                 float* __restrict__ cn) {
    int b = blockIdx.x >> 3;
    int nc = blockIdx.x & 7;  // 8 chunks of 128 rows
    int tid = threadIdx.x;
    float s0 = 0.f, s1 = 0.f;
    for (int n = nc * 128; n < nc * 128 + 128; n++) {
        size_t base = ((size_t)(b * Nc + n)) * Kc;
        s0 += C[base + tid];
        s1 += C[base + 256 + tid];
    }
    atomicAdd(&cn[b * Kc + tid], s0);
    atomicAdd(&cn[b * Kc + 256 + tid], s1);
}

// ---------------- kernel 3: kl scalar ----------------
__global__ __launch_bounds__(256) void kl_kernel(const float* __restrict__ C,
                                                 const float* __restrict__ cn,
                                                 float* __restrict__ klout) {
    __shared__ float cns[Kc];
    __shared__ float red[4];
    int b = blockIdx.x >> 6;
    int nc = blockIdx.x & 63;  // 64 chunks of 16 rows
    int tid = threadIdx.x;
    cns[tid] = cn[b * Kc + tid] + EPSc;
    cns[tid + 256] = cn[b * Kc + 256 + tid] + EPSc;
    __syncthreads();
    float kacc = 0.f;
    for (int r = 0; r < 16; r++) {
        int n = nc * 16 + r;
        size_t base = ((size_t)(b * Nc + n)) * Kc;
        float c0 = C[base + tid], c1 = C[base + 256 + tid];
        float p0 = c0 * c0 / cns[tid];
        float p1 = c1 * c1 / cns[tid + 256];
        float v = waveReduceSum(p0 + p1);
        if ((tid & 63) == 0) red[tid >> 6] = v;
        __syncthreads();
        float pn = red[0] + red[1] + red[2] + red[3] + EPSc;
        __syncthreads();
        float P0 = p0 / pn, P1 = p1 / pn;
        kacc += P0 * (logf(P0 + EPSc) - logf(c0 + EPSc)) +
                P1 * (logf(P1 + EPSc) - logf(c1 + EPSc));
    }
    float v = waveReduceSum(kacc);
    if ((tid & 63) == 0) red[tid >> 6] = v;
    __syncthreads();
    if (tid == 0) atomicAdd(klout, 100.f * (red[0] + red[1] + red[2] + red[3]));
}

// ---------------- kernel 4: V[b,k,f] = sum_n C[b,n,k]*Q[b,n,f] ----------------
__global__ __launch_bounds__(256) void v_kernel(const float* __restrict__ C,
                                                const float* __restrict__ Q,
                                                float* __restrict__ V) {
    __shared__ float Cs[16][68];
    __shared__ float Qs[16][68];
    int b = blockIdx.y;
    int kt = blockIdx.x >> 2;  // 8 k-tiles of 64
    int ft = blockIdx.x & 3;   // 4 f-tiles of 64
    int k0 = kt * 64, f0 = ft * 64;
    int tid = threadIdx.x;
    int ty = tid >> 4, tx = tid & 15;
    int li = tid >> 4, lj = tid & 15;
    float acc[4][4];
#pragma unroll
    for (int r = 0; r < 4; r++)
#pragma unroll
        for (int c = 0; c < 4; c++) acc[r][c] = 0.f;

    for (int n0 = 0; n0 < Nc; n0 += 16) {
        float4 cv = *(const float4*)(C + ((size_t)(b * Nc + n0 + li)) * Kc + k0 + lj * 4);
        float4 qv = *(const float4*)(Q + ((size_t)(b * Nc + n0 + li)) * Fc + f0 + lj * 4);
        __syncthreads();
        *(float4*)&Cs[li][lj * 4] = cv;
        *(float4*)&Qs[li][lj * 4] = qv;
        __syncthreads();
#pragma unroll
        for (int i = 0; i < 16; i++) {
            float4 a = *(const float4*)&Cs[i][ty * 4];
            float4 bb = *(const float4*)&Qs[i][tx * 4];
            acc[0][0] += a.x * bb.x; acc[0][1] += a.x * bb.y; acc[0][2] += a.x * bb.z; acc[0][3] += a.x * bb.w;
            acc[1][0] += a.y * bb.x; acc[1][1] += a.y * bb.y; acc[1][2] += a.y * bb.z; acc[1][3] += a.y * bb.w;
            acc[2][0] += a.z * bb.x; acc[2][1] += a.z * bb.y; acc[2][2] += a.z * bb.z; acc[2][3] += a.z * bb.w;
            acc[3][0] += a.w * bb.x; acc[3][1] += a.w * bb.y; acc[3][2] += a.w * bb.z; acc[3][3] += a.w * bb.w;
        }
    }
#pragma unroll
    for (int r = 0; r < 4; r++) {
        float4 o = make_float4(acc[r][0], acc[r][1], acc[r][2], acc[r][3]);
        *(float4*)(V + ((size_t)(b * Kc + k0 + ty * 4 + r)) * Fc + f0 + tx * 4) = o;
    }
}

// ---------------- kernel 5: out = leaky_relu(V @ W^T + b) ----------------
__global__ __launch_bounds__(256) void out_kernel(const float* __restrict__ V,
                                                  const float* __restrict__ W,
                                                  const float* __restrict__ bias,
                                                  float* __restrict__ out) {
    __shared__ float Vs[16][68];
    __shared__ float Ws[16][68];
    int m0 = blockIdx.x * 64;  // 128 row tiles over B*K=8192
    int o0 = blockIdx.y * 64;  // 4 col tiles over DOUT=256
    int tid = threadIdx.x;
    int ty = tid >> 4, tx = tid & 15;
    int j = tid & 63, i4 = tid >> 6;
    float acc[4][4];
#pragma unroll
    for (int r = 0; r < 4; r++)
#pragma unroll
        for (int c = 0; c < 4; c++) acc[r][c] = 0.f;

    for (int f0 = 0; f0 < Fc; f0 += 16) {
        float4 vv = *(const float4*)(V + (size_t)(m0 + j) * Fc + f0 + i4 * 4);
        float4 wv = *(const float4*)(W + (size_t)(o0 + j) * Fc + f0 + i4 * 4);
        __syncthreads();
        Vs[i4 * 4 + 0][j] = vv.x; Vs[i4 * 4 + 1][j] = vv.y;
        Vs[i4 * 4 + 2][j] = vv.z; Vs[i4 * 4 + 3][j] = vv.w;
        Ws[i4 * 4 + 0][j] = wv.x; Ws[i4 * 4 + 1][j] = wv.y;
        Ws[i4 * 4 + 2][j] = wv.z; Ws[i4 * 4 + 3][j] = wv.w;
        __syncthreads();
#pragma unroll
        for (int i = 0; i < 16; i++) {
            float4 a = *(const float4*)&Vs[i][ty * 4];
            float4 bb = *(const float4*)&Ws[i][tx * 4];
            acc[0][0] += a.x * bb.x; acc[0][1] += a.x * bb.y; acc[0][2] += a.x * bb.z; acc[0][3] += a.x * bb.w;
            acc[1][0] += a.y * bb.x; acc[1][1] += a.y * bb.y; acc[1][2] += a.y * bb.z; acc[1][3] += a.y * bb.w;
            acc[2][0] += a.z * bb.x; acc[2][1] += a.z * bb.y; acc[2][2] += a.z * bb.z; acc[2][3] += a.z * bb.w;
            acc[3][0] += a.w * bb.x; acc[3][1] += a.w * bb.y; acc[3][2] += a.w * bb.z; acc[3][3] += a.w * bb.w;
        }
    }
    float4 bv = *(const float4*)(bias + o0 + tx * 4);
#pragma unroll
    for (int r = 0; r < 4; r++) {
        float4 o;
        float x;
        x = acc[r][0] + bv.x; o.x = x > 0.f ? x : 0.01f * x;
        x = acc[r][1] + bv.y; o.y = x > 0.f ? x : 0.01f * x;
        x = acc[r][2] + bv.z; o.z = x > 0.f ? x : 0.01f * x;
        x = acc[r][3] + bv.w; o.w = x > 0.f ? x : 0.01f * x;
        *(float4*)(out + (size_t)(m0 + ty * 4 + r) * DOUTc + o0 + tx * 4) = o;
    }
}

extern "C" void kernel_launch(void* const* d_in, const int* in_sizes, int n_in,
                              void* d_out, int out_size, void* d_ws, size_t ws_size,
                              hipStream_t stream) {
    const float* Q = (const float*)d_in[0];
    const float* keys = (const float*)d_in[1];
    const float* conv_w = (const float*)d_in[2];
    const float* lin_w = (const float*)d_in[3];
    const float* lin_b = (const float*)d_in[4];
    const int* mask = (const int*)d_in[5];

    float* out = (float*)d_out;
    float* kl = out + (size_t)Bc * Kc * DOUTc;  // last element

    float* ws = (float*)d_ws;
    float* C = ws;                              // 16*1024*512
    float* k2 = C + (size_t)Bc * Nc * Kc;       // 4096
    float* cn = k2 + (size_t)Hc * Kc;           // 8192
    float* V = cn + (size_t)Bc * Kc;            // 16*512*256

    hipMemsetAsync(cn, 0, (size_t)Bc * Kc * sizeof(float), stream);
    hipMemsetAsync(kl, 0, sizeof(float), stream);

    k2_kernel<<<Hc * Kc / 256, 256, 0, stream>>>(keys, k2);
    compute_C_kernel<<<Bc * Nc / ROWS, 256, 0, stream>>>(Q, keys, conv_w, mask, k2, C);
    cn_kernel<<<128, 256, 0, stream>>>(C, cn);
    kl_kernel<<<1024, 256, 0, stream>>>(C, cn, kl);
    v_kernel<<<dim3(32, Bc), 256, 0, stream>>>(C, Q, V);
    out_kernel<<<dim3(128, 4), 256, 0, stream>>>(V, lin_w, lin_b, out);
}

// Round 2
// 449.156 us; speedup vs baseline: 2.6420x; 2.6420x over previous
//
#include <hip/hip_runtime.h>
#include <math.h>

#define Bc 16
#define Nc 1024
#define Fc 256
#define Hc 8
#define Kc 512
#define DOUTc 256
#define EPSc 1e-8f

typedef short v8s __attribute__((ext_vector_type(8)));
typedef float v4f __attribute__((ext_vector_type(4)));

__device__ __forceinline__ float waveReduceSum(float v) {
    v += __shfl_xor(v, 32); v += __shfl_xor(v, 16); v += __shfl_xor(v, 8);
    v += __shfl_xor(v, 4);  v += __shfl_xor(v, 2);  v += __shfl_xor(v, 1);
    return v;
}

__device__ __forceinline__ unsigned short f2bf(float f) {
    unsigned int u = __float_as_uint(f);
    u = (u + 0x7fffu + ((u >> 16) & 1u)) >> 16;   // RNE
    return (unsigned short)u;
}

// ---- prep: fp32 -> bf16 for Q and keys; fp32 row sum-of-squares ----
__global__ __launch_bounds__(256) void prep_kernel(
    const float* __restrict__ Q, const float* __restrict__ keys,
    unsigned short* __restrict__ Qb, unsigned short* __restrict__ Kb,
    float* __restrict__ q2g, float* __restrict__ k2g) {
    int row = blockIdx.x * 4 + (threadIdx.x >> 6);
    int l = threadIdx.x & 63;
    const float* src; unsigned short* dst; float* sq;
    if (row < Bc * Nc) {
        src = Q + (size_t)row * Fc; dst = Qb + (size_t)row * Fc; sq = q2g + row;
    } else {
        int r = row - Bc * Nc;
        src = keys + (size_t)r * Fc; dst = Kb + (size_t)r * Fc; sq = k2g + r;
    }
    float4 v = *(const float4*)(src + l * 4);
    float s = v.x * v.x + v.y * v.y + v.z * v.z + v.w * v.w;
    ushort4 o = make_ushort4(f2bf(v.x), f2bf(v.y), f2bf(v.z), f2bf(v.w));
    *(ushort4*)(dst + l * 4) = o;
    s = waveReduceSum(s);
    if (l == 0) *sq = s;
}

// ---- fused distance-GEMM (MFMA bf16) -> cauchy -> head-norm/mix -> softmax -> C ----
// block: 256 thr = 4 waves; rows = 16 (gr0..gr0+15), cols = 512 (wave wv owns 128)
__global__ __launch_bounds__(256) void cmfma_kernel(
    const unsigned short* __restrict__ Qb, const unsigned short* __restrict__ Kb,
    const float* __restrict__ q2g, const float* __restrict__ k2g,
    const float* __restrict__ conv_w, const int* __restrict__ mask,
    float* __restrict__ C) {
    __shared__ float redbuf[4][16];
    const int tid = threadIdx.x;
    const int wv = tid >> 6, L = tid & 63;
    const int qd = L >> 4, li = L & 15;
    const int gr0 = blockIdx.x * 16;  // flat row over B*N

    float q2r[4], mrow[4];
#pragma unroll
    for (int r = 0; r < 4; r++) {
        int gr = gr0 + qd * 4 + r;
        q2r[r] = q2g[gr];
        mrow[r] = (float)mask[gr];
    }

    // A-frags for all 8 k-steps (K=256 = 8*32), persistent in regs.
    // A[m=li][k=qd*8+j] (verified layout, learn_hip m89/m120)
    v8s A[8];
    {
        const unsigned short* qa = Qb + (size_t)(gr0 + li) * Fc + qd * 8;
#pragma unroll
        for (int ks = 0; ks < 8; ks++) A[ks] = *(const v8s*)(qa + ks * 32);
    }

    // B-frag base: col = h*512 + wv*128 + ct*16 + li; elem = col*256 + ks*32 + qd*8
    const unsigned short* kbase = Kb + (size_t)(wv * 128 + li) * Fc + qd * 8;

    v4f D[8], S[8];
#pragma unroll
    for (int ct = 0; ct < 8; ct++) {
        D[ct] = (v4f){0.f, 0.f, 0.f, 0.f};
        S[ct] = (v4f){0.f, 0.f, 0.f, 0.f};
    }

    v8s Bc0[8], Bn[8];
#pragma unroll
    for (int ct = 0; ct < 8; ct++) Bc0[ct] = *(const v8s*)(kbase + ct * 4096);

#define KSTEP(kk, CUR, NXT)                                                        \
    do {                                                                           \
        int itn = (h * 8 + (kk) + 1) & 63;                                         \
        const unsigned short* pb =                                                 \
            kbase + (size_t)(itn >> 3) * 131072 + (size_t)(itn & 7) * 32;          \
        _Pragma("unroll") for (int ct = 0; ct < 8; ct++)                           \
            NXT[ct] = *(const v8s*)(pb + ct * 4096);                               \
        _Pragma("unroll") for (int ct = 0; ct < 8; ct++)                           \
            D[ct] = __builtin_amdgcn_mfma_f32_16x16x32_bf16(A[kk], CUR[ct],        \
                                                            D[ct], 0, 0, 0);      \
    } while (0)

    for (int h = 0; h < Hc; ++h) {
        float wh = conv_w[h];
        KSTEP(0, Bc0, Bn); KSTEP(1, Bn, Bc0);
        KSTEP(2, Bc0, Bn); KSTEP(3, Bn, Bc0);
        KSTEP(4, Bc0, Bn); KSTEP(5, Bn, Bc0);
        KSTEP(6, Bc0, Bn); KSTEP(7, Bn, Bc0);

        // epilogue: t = 1/(1+d2), per-row sum over this head's 512 cols
        float rs[4] = {0.f, 0.f, 0.f, 0.f};
#pragma unroll
        for (int ct = 0; ct < 8; ct++) {
            float k2v = k2g[h * Kc + wv * 128 + ct * 16 + li];
#pragma unroll
            for (int r = 0; r < 4; r++) {
                float d2 = fmaxf(q2r[r] + k2v - 2.f * D[ct][r], 0.f) * mrow[r];
                float t = __builtin_amdgcn_rcpf(1.f + d2);
                D[ct][r] = t;
                rs[r] += t;
            }
        }
#pragma unroll
        for (int r = 0; r < 4; r++) {
            rs[r] += __shfl_xor(rs[r], 1, 16);
            rs[r] += __shfl_xor(rs[r], 2, 16);
            rs[r] += __shfl_xor(rs[r], 4, 16);
            rs[r] += __shfl_xor(rs[r], 8, 16);
        }
        if (li == 0) {
#pragma unroll
            for (int r = 0; r < 4; r++) redbuf[wv][qd * 4 + r] = rs[r];
        }
        __syncthreads();
        float sc[4];
#pragma unroll
        for (int r = 0; r < 4; r++) {
            int rw = qd * 4 + r;
            float tot = redbuf[0][rw] + redbuf[1][rw] + redbuf[2][rw] + redbuf[3][rw];
            sc[r] = wh * __builtin_amdgcn_rcpf(tot);
        }
        __syncthreads();
#pragma unroll
        for (int ct = 0; ct < 8; ct++)
#pragma unroll
            for (int r = 0; r < 4; r++) {
                S[ct][r] += sc[r] * D[ct][r];
                D[ct][r] = 0.f;
            }
    }
#undef KSTEP

    // softmax over the 512 columns
    float mx[4] = {-1e30f, -1e30f, -1e30f, -1e30f};
#pragma unroll
    for (int ct = 0; ct < 8; ct++)
#pragma unroll
        for (int r = 0; r < 4; r++) mx[r] = fmaxf(mx[r], S[ct][r]);
#pragma unroll
    for (int r = 0; r < 4; r++) {
        mx[r] = fmaxf(mx[r], __shfl_xor(mx[r], 1, 16));
        mx[r] = fmaxf(mx[r], __shfl_xor(mx[r], 2, 16));
        mx[r] = fmaxf(mx[r], __shfl_xor(mx[r], 4, 16));
        mx[r] = fmaxf(mx[r], __shfl_xor(mx[r], 8, 16));
    }
    if (li == 0) {
#pragma unroll
        for (int r = 0; r < 4; r++) redbuf[wv][qd * 4 + r] = mx[r];
    }
    __syncthreads();
#pragma unroll
    for (int r = 0; r < 4; r++) {
        int rw = qd * 4 + r;
        mx[r] = fmaxf(fmaxf(redbuf[0][rw], redbuf[1][rw]),
                      fmaxf(redbuf[2][rw], redbuf[3][rw]));
    }
    __syncthreads();
    float es[4] = {0.f, 0.f, 0.f, 0.f};
#pragma unroll
    for (int ct = 0; ct < 8; ct++)
#pragma unroll
        for (int r = 0; r < 4; r++) {
            float e = __expf(S[ct][r] - mx[r]);
            S[ct][r] = e;
            es[r] += e;
        }
#pragma unroll
    for (int r = 0; r < 4; r++) {
        es[r] += __shfl_xor(es[r], 1, 16);
        es[r] += __shfl_xor(es[r], 2, 16);
        es[r] += __shfl_xor(es[r], 4, 16);
        es[r] += __shfl_xor(es[r], 8, 16);
    }
    if (li == 0) {
#pragma unroll
        for (int r = 0; r < 4; r++) redbuf[wv][qd * 4 + r] = es[r];
    }
    __syncthreads();
    float inv[4];
#pragma unroll
    for (int r = 0; r < 4; r++) {
        int rw = qd * 4 + r;
        float tot = redbuf[0][rw] + redbuf[1][rw] + redbuf[2][rw] + redbuf[3][rw];
        inv[r] = mrow[r] / tot;
    }
#pragma unroll
    for (int ct = 0; ct < 8; ct++)
#pragma unroll
        for (int r = 0; r < 4; r++)
            C[(size_t)(gr0 + qd * 4 + r) * Kc + wv * 128 + ct * 16 + li] =
                S[ct][r] * inv[r];
}

// ---------------- cn[b,k] = sum_n C[b,n,k] ----------------
__global__ __launch_bounds__(256) void cn_kernel(const float* __restrict__ C,
                                                 float* __restrict__ cn) {
    int b = blockIdx.x >> 3;
    int nc = blockIdx.x & 7;
    int tid = threadIdx.x;
    float s0 = 0.f, s1 = 0.f;
    for (int n = nc * 128; n < nc * 128 + 128; n++) {
        size_t base = ((size_t)(b * Nc + n)) * Kc;
        s0 += C[base + tid];
        s1 += C[base + 256 + tid];
    }
    atomicAdd(&cn[b * Kc + tid], s0);
    atomicAdd(&cn[b * Kc + 256 + tid], s1);
}

// ---------------- kl scalar ----------------
__global__ __launch_bounds__(256) void kl_kernel(const float* __restrict__ C,
                                                 const float* __restrict__ cn,
                                                 float* __restrict__ klout) {
    __shared__ float cns[Kc];
    __shared__ float red[4];
    int b = blockIdx.x >> 6;
    int nc = blockIdx.x & 63;
    int tid = threadIdx.x;
    cns[tid] = cn[b * Kc + tid] + EPSc;
    cns[tid + 256] = cn[b * Kc + 256 + tid] + EPSc;
    __syncthreads();
    float kacc = 0.f;
    for (int r = 0; r < 16; r++) {
        int n = nc * 16 + r;
        size_t base = ((size_t)(b * Nc + n)) * Kc;
        float c0 = C[base + tid], c1 = C[base + 256 + tid];
        float p0 = c0 * c0 / cns[tid];
        float p1 = c1 * c1 / cns[tid + 256];
        float v = waveReduceSum(p0 + p1);
        if ((tid & 63) == 0) red[tid >> 6] = v;
        __syncthreads();
        float pn = red[0] + red[1] + red[2] + red[3] + EPSc;
        __syncthreads();
        float P0 = p0 / pn, P1 = p1 / pn;
        kacc += P0 * (logf(P0 + EPSc) - logf(c0 + EPSc)) +
                P1 * (logf(P1 + EPSc) - logf(c1 + EPSc));
    }
    float v = waveReduceSum(kacc);
    if ((tid & 63) == 0) red[tid >> 6] = v;
    __syncthreads();
    if (tid == 0) atomicAdd(klout, 100.f * (red[0] + red[1] + red[2] + red[3]));
}

// ---------------- V[b,k,f] = sum_n C[b,n,k]*Q[b,n,f] ----------------
__global__ __launch_bounds__(256) void v_kernel(const float* __restrict__ C,
                                                const float* __restrict__ Q,
                                                float* __restrict__ V) {
    __shared__ float Cs[16][68];
    __shared__ float Qs[16][68];
    int b = blockIdx.y;
    int kt = blockIdx.x >> 2;
    int ft = blockIdx.x & 3;
    int k0 = kt * 64, f0 = ft * 64;
    int tid = threadIdx.x;
    int ty = tid >> 4, tx = tid & 15;
    int li = tid >> 4, lj = tid & 15;
    float acc[4][4];
#pragma unroll
    for (int r = 0; r < 4; r++)
#pragma unroll
        for (int c = 0; c < 4; c++) acc[r][c] = 0.f;

    for (int n0 = 0; n0 < Nc; n0 += 16) {
        float4 cv = *(const float4*)(C + ((size_t)(b * Nc + n0 + li)) * Kc + k0 + lj * 4);
        float4 qv = *(const float4*)(Q + ((size_t)(b * Nc + n0 + li)) * Fc + f0 + lj * 4);
        __syncthreads();
        *(float4*)&Cs[li][lj * 4] = cv;
        *(float4*)&Qs[li][lj * 4] = qv;
        __syncthreads();
#pragma unroll
        for (int i = 0; i < 16; i++) {
            float4 a = *(const float4*)&Cs[i][ty * 4];
            float4 bb = *(const float4*)&Qs[i][tx * 4];
            acc[0][0] += a.x * bb.x; acc[0][1] += a.x * bb.y; acc[0][2] += a.x * bb.z; acc[0][3] += a.x * bb.w;
            acc[1][0] += a.y * bb.x; acc[1][1] += a.y * bb.y; acc[1][2] += a.y * bb.z; acc[1][3] += a.y * bb.w;
            acc[2][0] += a.z * bb.x; acc[2][1] += a.z * bb.y; acc[2][2] += a.z * bb.z; acc[2][3] += a.z * bb.w;
            acc[3][0] += a.w * bb.x; acc[3][1] += a.w * bb.y; acc[3][2] += a.w * bb.z; acc[3][3] += a.w * bb.w;
        }
    }
#pragma unroll
    for (int r = 0; r < 4; r++) {
        float4 o = make_float4(acc[r][0], acc[r][1], acc[r][2], acc[r][3]);
        *(float4*)(V + ((size_t)(b * Kc + k0 + ty * 4 + r)) * Fc + f0 + tx * 4) = o;
    }
}

// ---------------- out = leaky_relu(V @ W^T + b) ----------------
__global__ __launch_bounds__(256) void out_kernel(const float* __restrict__ V,
                                                  const float* __restrict__ W,
                                                  const float* __restrict__ bias,
                                                  float* __restrict__ out) {
    __shared__ float Vs[16][68];
    __shared__ float Ws[16][68];
    int m0 = blockIdx.x * 64;
    int o0 = blockIdx.y * 64;
    int tid = threadIdx.x;
    int ty = tid >> 4, tx = tid & 15;
    int j = tid & 63, i4 = tid >> 6;
    float acc[4][4];
#pragma unroll
    for (int r = 0; r < 4; r++)
#pragma unroll
        for (int c = 0; c < 4; c++) acc[r][c] = 0.f;

    for (int f0 = 0; f0 < Fc; f0 += 16) {
        float4 vv = *(const float4*)(V + (size_t)(m0 + j) * Fc + f0 + i4 * 4);
        float4 wv = *(const float4*)(W + (size_t)(o0 + j) * Fc + f0 + i4 * 4);
        __syncthreads();
        Vs[i4 * 4 + 0][j] = vv.x; Vs[i4 * 4 + 1][j] = vv.y;
        Vs[i4 * 4 + 2][j] = vv.z; Vs[i4 * 4 + 3][j] = vv.w;
        Ws[i4 * 4 + 0][j] = wv.x; Ws[i4 * 4 + 1][j] = wv.y;
        Ws[i4 * 4 + 2][j] = wv.z; Ws[i4 * 4 + 3][j] = wv.w;
        __syncthreads();
#pragma unroll
        for (int i = 0; i < 16; i++) {
            float4 a = *(const float4*)&Vs[i][ty * 4];
            float4 bb = *(const float4*)&Ws[i][tx * 4];
            acc[0][0] += a.x * bb.x; acc[0][1] += a.x * bb.y; acc[0][2] += a.x * bb.z; acc[0][3] += a.x * bb.w;
            acc[1][0] += a.y * bb.x; acc[1][1] += a.y * bb.y; acc[1][2] += a.y * bb.z; acc[1][3] += a.y * bb.w;
            acc[2][0] += a.z * bb.x; acc[2][1] += a.z * bb.y; acc[2][2] += a.z * bb.z; acc[2][3] += a.z * bb.w;
            acc[3][0] += a.w * bb.x; acc[3][1] += a.w * bb.y; acc[3][2] += a.w * bb.z; acc[3][3] += a.w * bb.w;
        }
    }
    float4 bv = *(const float4*)(bias + o0 + tx * 4);
#pragma unroll
    for (int r = 0; r < 4; r++) {
        float4 o;
        float x;
        x = acc[r][0] + bv.x; o.x = x > 0.f ? x : 0.01f * x;
        x = acc[r][1] + bv.y; o.y = x > 0.f ? x : 0.01f * x;
        x = acc[r][2] + bv.z; o.z = x > 0.f ? x : 0.01f * x;
        x = acc[r][3] + bv.w; o.w = x > 0.f ? x : 0.01f * x;
        *(float4*)(out + (size_t)(m0 + ty * 4 + r) * DOUTc + o0 + tx * 4) = o;
    }
}

extern "C" void kernel_launch(void* const* d_in, const int* in_sizes, int n_in,
                              void* d_out, int out_size, void* d_ws, size_t ws_size,
                              hipStream_t stream) {
    const float* Q = (const float*)d_in[0];
    const float* keys = (const float*)d_in[1];
    const float* conv_w = (const float*)d_in[2];
    const float* lin_w = (const float*)d_in[3];
    const float* lin_b = (const float*)d_in[4];
    const int* mask = (const int*)d_in[5];

    float* out = (float*)d_out;
    float* kl = out + (size_t)Bc * Kc * DOUTc;

    float* ws = (float*)d_ws;
    float* C = ws;                               // 8,388,608 f
    float* k2 = C + (size_t)Bc * Nc * Kc;        // 4,096 f
    float* cn = k2 + (size_t)Hc * Kc;            // 8,192 f
    float* V = cn + (size_t)Bc * Kc;             // 2,097,152 f
    float* q2 = V + (size_t)Bc * Kc * Fc;        // 16,384 f
    unsigned short* Qb = (unsigned short*)(q2 + (size_t)Bc * Nc);  // 4,194,304 us
    unsigned short* Kb = Qb + (size_t)Bc * Nc * Fc;                // 1,048,576 us

    hipMemsetAsync(cn, 0, (size_t)Bc * Kc * sizeof(float), stream);
    hipMemsetAsync(kl, 0, sizeof(float), stream);

    prep_kernel<<<(Bc * Nc + Hc * Kc) / 4, 256, 0, stream>>>(Q, keys, Qb, Kb, q2, k2);
    cmfma_kernel<<<Bc * Nc / 16, 256, 0, stream>>>(Qb, Kb, q2, k2, conv_w, mask, C);
    cn_kernel<<<128, 256, 0, stream>>>(C, cn);
    kl_kernel<<<1024, 256, 0, stream>>>(C, cn, kl);
    v_kernel<<<dim3(32, Bc), 256, 0, stream>>>(C, Q, V);
    out_kernel<<<dim3(128, 4), 256, 0, stream>>>(V, lin_w, lin_b, out);
}

// Round 3
// 293.803 us; speedup vs baseline: 4.0390x; 1.5288x over previous
//
#include <hip/hip_runtime.h>
#include <math.h>

#define Bc 16
#define Nc 1024
#define Fc 256
#define Hc 8
#define Kc 512
#define DOUTc 256
#define EPSc 1e-8f

typedef short v8s __attribute__((ext_vector_type(8)));
typedef float v4f __attribute__((ext_vector_type(4)));

__device__ __forceinline__ float waveReduceSum(float v) {
    v += __shfl_xor(v, 32); v += __shfl_xor(v, 16); v += __shfl_xor(v, 8);
    v += __shfl_xor(v, 4);  v += __shfl_xor(v, 2);  v += __shfl_xor(v, 1);
    return v;
}

__device__ __forceinline__ unsigned short f2bf(float f) {
    unsigned int u = __float_as_uint(f);
    u = (u + 0x7fffu + ((u >> 16) & 1u)) >> 16;   // RNE
    return (unsigned short)u;
}

// ---- prep: Q fp32 -> bf16 row-major; q2 row sums ----
__global__ __launch_bounds__(256) void prep_kernel(
    const float* __restrict__ Q, unsigned short* __restrict__ Qb,
    float* __restrict__ q2g) {
    int row = blockIdx.x * 4 + (threadIdx.x >> 6);
    int l = threadIdx.x & 63;
    const float* src = Q + (size_t)row * Fc;
    float4 v = *(const float4*)(src + l * 4);
    float s = v.x * v.x + v.y * v.y + v.z * v.z + v.w * v.w;
    ushort4 o = make_ushort4(f2bf(v.x), f2bf(v.y), f2bf(v.z), f2bf(v.w));
    *(ushort4*)(Qb + (size_t)row * Fc + l * 4) = o;
    s = waveReduceSum(s);
    if (l == 0) q2g[row] = s;
}

// ---- k2 row sums of keys ----
__global__ __launch_bounds__(256) void k2_kernel(const float* __restrict__ keys,
                                                 float* __restrict__ k2g) {
    int c = blockIdx.x * 256 + threadIdx.x;  // 0..4095
    const float4* kp = (const float4*)(keys + (size_t)c * Fc);
    float s = 0.f;
#pragma unroll 8
    for (int i = 0; i < Fc / 4; i++) {
        float4 v = kp[i];
        s += v.x * v.x + v.y * v.y + v.z * v.z + v.w * v.w;
    }
    k2g[c] = s;
}

// ---- pack keys into MFMA B-frag streaming order ----
// chunk ci = (h*4+wv)*64 + ks*8 + ct ; within chunk: lane L holds 8 bf16 (16 B)
// element: col = h*512 + wv*128 + ct*16 + li ; k = ks*32 + qd*8 + j
__global__ __launch_bounds__(256) void kpack_kernel(const float* __restrict__ keys,
                                                    unsigned short* __restrict__ Kp) {
    int t = blockIdx.x * 256 + threadIdx.x;  // 0..524287
    int lane = t & 63, ci = t >> 6;
    int ct = ci & 7, ks = (ci >> 3) & 7, wv = (ci >> 6) & 3, h = ci >> 8;
    int qd = lane >> 4, li = lane & 15;
    int col = h * 512 + wv * 128 + ct * 16 + li;
    const float* src = keys + (size_t)col * Fc + ks * 32 + qd * 8;
    float4 a = *(const float4*)src;
    float4 b = *(const float4*)(src + 4);
    unsigned short o[8] = {f2bf(a.x), f2bf(a.y), f2bf(a.z), f2bf(a.w),
                           f2bf(b.x), f2bf(b.y), f2bf(b.z), f2bf(b.w)};
    *(ushort4*)(Kp + (size_t)t * 8) = make_ushort4(o[0], o[1], o[2], o[3]);
    *(ushort4*)(Kp + (size_t)t * 8 + 4) = make_ushort4(o[4], o[5], o[6], o[7]);
}

// ---- fused distance-GEMM (MFMA bf16) -> cauchy -> head-norm/mix -> softmax -> C, cn ----
__global__ __launch_bounds__(256) void cmfma_kernel(
    const unsigned short* __restrict__ Qb, const unsigned short* __restrict__ Kp,
    const float* __restrict__ q2g, const float* __restrict__ k2g,
    const float* __restrict__ conv_w, const int* __restrict__ mask,
    float* __restrict__ C, float* __restrict__ cn) {
    __shared__ float redbuf[4][16];
    const int tid = threadIdx.x;
    const int wv = tid >> 6, L = tid & 63;
    const int qd = L >> 4, li = L & 15;
    const int gr0 = blockIdx.x * 16;  // flat row over B*N
    const int b = gr0 >> 10;

    float q2r[4], mrow[4];
#pragma unroll
    for (int r = 0; r < 4; r++) {
        int gr = gr0 + qd * 4 + r;
        q2r[r] = q2g[gr];
        mrow[r] = (float)mask[gr];
    }

    // A-frags (16 rows x K=256), persistent
    v8s A[8];
    {
        const unsigned short* qa = Qb + (size_t)(gr0 + li) * Fc + qd * 8;
#pragma unroll
        for (int ks = 0; ks < 8; ks++) A[ks] = *(const v8s*)(qa + ks * 32);
    }

    v4f D[8], S[8];
#pragma unroll
    for (int ct = 0; ct < 8; ct++) {
        D[ct] = (v4f){0.f, 0.f, 0.f, 0.f};
        S[ct] = (v4f){0.f, 0.f, 0.f, 0.f};
    }

    // packed base for this wave's lane; chunk stride = 512 elems (1 KB)
    const unsigned short* kwbase = Kp + (size_t)L * 8;

    v8s Bc0[8], Bn[8];
    {
        const unsigned short* p0 = kwbase + (size_t)(wv * 64) * 512;
#pragma unroll
        for (int ct = 0; ct < 8; ct++) Bc0[ct] = *(const v8s*)(p0 + ct * 512);
    }

#define KSTEP(kk, CUR, NXT)                                                        \
    do {                                                                           \
        int hn = h * 8 + (kk) + 1;                                                 \
        int hh = (hn >> 3) & 7, kn = hn & 7;                                       \
        const unsigned short* pb =                                                 \
            kwbase + (size_t)(((hh * 4 + wv) * 64 + kn * 8)) * 512;                \
        _Pragma("unroll") for (int ct = 0; ct < 8; ct++)                           \
            NXT[ct] = *(const v8s*)(pb + ct * 512);                                \
        _Pragma("unroll") for (int ct = 0; ct < 8; ct++)                           \
            D[ct] = __builtin_amdgcn_mfma_f32_16x16x32_bf16(A[kk], CUR[ct],        \
                                                            D[ct], 0, 0, 0);      \
    } while (0)

    for (int h = 0; h < Hc; ++h) {
        float wh = conv_w[h];
        KSTEP(0, Bc0, Bn); KSTEP(1, Bn, Bc0);
        KSTEP(2, Bc0, Bn); KSTEP(3, Bn, Bc0);
        KSTEP(4, Bc0, Bn); KSTEP(5, Bn, Bc0);
        KSTEP(6, Bc0, Bn); KSTEP(7, Bn, Bc0);

        float rs[4] = {0.f, 0.f, 0.f, 0.f};
#pragma unroll
        for (int ct = 0; ct < 8; ct++) {
            float k2v = k2g[h * Kc + wv * 128 + ct * 16 + li];
#pragma unroll
            for (int r = 0; r < 4; r++) {
                float d2 = fmaxf(q2r[r] + k2v - 2.f * D[ct][r], 0.f) * mrow[r];
                float t = __builtin_amdgcn_rcpf(1.f + d2);
                D[ct][r] = t;
                rs[r] += t;
            }
        }
#pragma unroll
        for (int r = 0; r < 4; r++) {
            rs[r] += __shfl_xor(rs[r], 1, 16);
            rs[r] += __shfl_xor(rs[r], 2, 16);
            rs[r] += __shfl_xor(rs[r], 4, 16);
            rs[r] += __shfl_xor(rs[r], 8, 16);
        }
        if (li == 0) {
#pragma unroll
            for (int r = 0; r < 4; r++) redbuf[wv][qd * 4 + r] = rs[r];
        }
        __syncthreads();
        float sc[4];
#pragma unroll
        for (int r = 0; r < 4; r++) {
            int rw = qd * 4 + r;
            float tot = redbuf[0][rw] + redbuf[1][rw] + redbuf[2][rw] + redbuf[3][rw];
            sc[r] = wh * __builtin_amdgcn_rcpf(tot);
        }
        __syncthreads();
#pragma unroll
        for (int ct = 0; ct < 8; ct++)
#pragma unroll
            for (int r = 0; r < 4; r++) {
                S[ct][r] += sc[r] * D[ct][r];
                D[ct][r] = 0.f;
            }
    }
#undef KSTEP

    // softmax over 512 columns
    float mx[4] = {-1e30f, -1e30f, -1e30f, -1e30f};
#pragma unroll
    for (int ct = 0; ct < 8; ct++)
#pragma unroll
        for (int r = 0; r < 4; r++) mx[r] = fmaxf(mx[r], S[ct][r]);
#pragma unroll
    for (int r = 0; r < 4; r++) {
        mx[r] = fmaxf(mx[r], __shfl_xor(mx[r], 1, 16));
        mx[r] = fmaxf(mx[r], __shfl_xor(mx[r], 2, 16));
        mx[r] = fmaxf(mx[r], __shfl_xor(mx[r], 4, 16));
        mx[r] = fmaxf(mx[r], __shfl_xor(mx[r], 8, 16));
    }
    if (li == 0) {
#pragma unroll
        for (int r = 0; r < 4; r++) redbuf[wv][qd * 4 + r] = mx[r];
    }
    __syncthreads();
#pragma unroll
    for (int r = 0; r < 4; r++) {
        int rw = qd * 4 + r;
        mx[r] = fmaxf(fmaxf(redbuf[0][rw], redbuf[1][rw]),
                      fmaxf(redbuf[2][rw], redbuf[3][rw]));
    }
    __syncthreads();
    float es[4] = {0.f, 0.f, 0.f, 0.f};
#pragma unroll
    for (int ct = 0; ct < 8; ct++)
#pragma unroll
        for (int r = 0; r < 4; r++) {
            float e = __expf(S[ct][r] - mx[r]);
            S[ct][r] = e;
            es[r] += e;
        }
#pragma unroll
    for (int r = 0; r < 4; r++) {
        es[r] += __shfl_xor(es[r], 1, 16);
        es[r] += __shfl_xor(es[r], 2, 16);
        es[r] += __shfl_xor(es[r], 4, 16);
        es[r] += __shfl_xor(es[r], 8, 16);
    }
    if (li == 0) {
#pragma unroll
        for (int r = 0; r < 4; r++) redbuf[wv][qd * 4 + r] = es[r];
    }
    __syncthreads();
    float inv[4];
#pragma unroll
    for (int r = 0; r < 4; r++) {
        int rw = qd * 4 + r;
        float tot = redbuf[0][rw] + redbuf[1][rw] + redbuf[2][rw] + redbuf[3][rw];
        inv[r] = mrow[r] / tot;
    }
#pragma unroll
    for (int ct = 0; ct < 8; ct++) {
        float colsum = 0.f;
#pragma unroll
        for (int r = 0; r < 4; r++) {
            float cv = S[ct][r] * inv[r];
            C[(size_t)(gr0 + qd * 4 + r) * Kc + wv * 128 + ct * 16 + li] = cv;
            colsum += cv;
        }
        colsum += __shfl_xor(colsum, 16);
        colsum += __shfl_xor(colsum, 32);
        if (qd == 0)
            atomicAdd(&cn[b * Kc + wv * 128 + ct * 16 + li], colsum);
    }
}

// ---------------- kl scalar ----------------
__global__ __launch_bounds__(256) void kl_kernel(const float* __restrict__ C,
                                                 const float* __restrict__ cn,
                                                 float* __restrict__ klout) {
    __shared__ float cns[Kc];
    __shared__ float red[4];
    int b = blockIdx.x >> 6;
    int nc = blockIdx.x & 63;
    int tid = threadIdx.x;
    cns[tid] = cn[b * Kc + tid] + EPSc;
    cns[tid + 256] = cn[b * Kc + 256 + tid] + EPSc;
    __syncthreads();
    float kacc = 0.f;
    for (int r = 0; r < 16; r++) {
        int n = nc * 16 + r;
        size_t base = ((size_t)(b * Nc + n)) * Kc;
        float c0 = C[base + tid], c1 = C[base + 256 + tid];
        float p0 = c0 * c0 / cns[tid];
        float p1 = c1 * c1 / cns[tid + 256];
        float v = waveReduceSum(p0 + p1);
        if ((tid & 63) == 0) red[tid >> 6] = v;
        __syncthreads();
        float pn = red[0] + red[1] + red[2] + red[3] + EPSc;
        __syncthreads();
        float P0 = p0 / pn, P1 = p1 / pn;
        kacc += P0 * __logf((P0 + EPSc) / (c0 + EPSc)) +
                P1 * __logf((P1 + EPSc) / (c1 + EPSc));
    }
    float v = waveReduceSum(kacc);
    if ((tid & 63) == 0) red[tid >> 6] = v;
    __syncthreads();
    if (tid == 0) atomicAdd(klout, 100.f * (red[0] + red[1] + red[2] + red[3]));
}

// ---------------- V[b,k,f] = sum_n C[b,n,k]*Q[b,n,f] ----------------
__global__ __launch_bounds__(256) void v_kernel(const float* __restrict__ C,
                                                const float* __restrict__ Q,
                                                float* __restrict__ V) {
    __shared__ float Cs[16][68];
    __shared__ float Qs[16][68];
    int b = blockIdx.y;
    int kt = blockIdx.x >> 2;
    int ft = blockIdx.x & 3;
    int k0 = kt * 64, f0 = ft * 64;
    int tid = threadIdx.x;
    int ty = tid >> 4, tx = tid & 15;
    int li = tid >> 4, lj = tid & 15;
    float acc[4][4];
#pragma unroll
    for (int r = 0; r < 4; r++)
#pragma unroll
        for (int c = 0; c < 4; c++) acc[r][c] = 0.f;

    for (int n0 = 0; n0 < Nc; n0 += 16) {
        float4 cv = *(const float4*)(C + ((size_t)(b * Nc + n0 + li)) * Kc + k0 + lj * 4);
        float4 qv = *(const float4*)(Q + ((size_t)(b * Nc + n0 + li)) * Fc + f0 + lj * 4);
        __syncthreads();
        *(float4*)&Cs[li][lj * 4] = cv;
        *(float4*)&Qs[li][lj * 4] = qv;
        __syncthreads();
#pragma unroll
        for (int i = 0; i < 16; i++) {
            float4 a = *(const float4*)&Cs[i][ty * 4];
            float4 bb = *(const float4*)&Qs[i][tx * 4];
            acc[0][0] += a.x * bb.x; acc[0][1] += a.x * bb.y; acc[0][2] += a.x * bb.z; acc[0][3] += a.x * bb.w;
            acc[1][0] += a.y * bb.x; acc[1][1] += a.y * bb.y; acc[1][2] += a.y * bb.z; acc[1][3] += a.y * bb.w;
            acc[2][0] += a.z * bb.x; acc[2][1] += a.z * bb.y; acc[2][2] += a.z * bb.z; acc[2][3] += a.z * bb.w;
            acc[3][0] += a.w * bb.x; acc[3][1] += a.w * bb.y; acc[3][2] += a.w * bb.z; acc[3][3] += a.w * bb.w;
        }
    }
#pragma unroll
    for (int r = 0; r < 4; r++) {
        float4 o = make_float4(acc[r][0], acc[r][1], acc[r][2], acc[r][3]);
        *(float4*)(V + ((size_t)(b * Kc + k0 + ty * 4 + r)) * Fc + f0 + tx * 4) = o;
    }
}

// ---------------- out = leaky_relu(V @ W^T + b) ----------------
__global__ __launch_bounds__(256) void out_kernel(const float* __restrict__ V,
                                                  const float* __restrict__ W,
                                                  const float* __restrict__ bias,
                                                  float* __restrict__ out) {
    __shared__ float Vs[16][68];
    __shared__ float Ws[16][68];
    int m0 = blockIdx.x * 64;
    int o0 = blockIdx.y * 64;
    int tid = threadIdx.x;
    int ty = tid >> 4, tx = tid & 15;
    int j = tid & 63, i4 = tid >> 6;
    float acc[4][4];
#pragma unroll
    for (int r = 0; r < 4; r++)
#pragma unroll
        for (int c = 0; c < 4; c++) acc[r][c] = 0.f;

    for (int f0 = 0; f0 < Fc; f0 += 16) {
        float4 vv = *(const float4*)(V + (size_t)(m0 + j) * Fc + f0 + i4 * 4);
        float4 wv = *(const float4*)(W + (size_t)(o0 + j) * Fc + f0 + i4 * 4);
        __syncthreads();
        Vs[i4 * 4 + 0][j] = vv.x; Vs[i4 * 4 + 1][j] = vv.y;
        Vs[i4 * 4 + 2][j] = vv.z; Vs[i4 * 4 + 3][j] = vv.w;
        Ws[i4 * 4 + 0][j] = wv.x; Ws[i4 * 4 + 1][j] = wv.y;
        Ws[i4 * 4 + 2][j] = wv.z; Ws[i4 * 4 + 3][j] = wv.w;
        __syncthreads();
#pragma unroll
        for (int i = 0; i < 16; i++) {
            float4 a = *(const float4*)&Vs[i][ty * 4];
            float4 bb = *(const float4*)&Ws[i][tx * 4];
            acc[0][0] += a.x * bb.x; acc[0][1] += a.x * bb.y; acc[0][2] += a.x * bb.z; acc[0][3] += a.x * bb.w;
            acc[1][0] += a.y * bb.x; acc[1][1] += a.y * bb.y; acc[1][2] += a.y * bb.z; acc[1][3] += a.y * bb.w;
            acc[2][0] += a.z * bb.x; acc[2][1] += a.z * bb.y; acc[2][2] += a.z * bb.z; acc[2][3] += a.z * bb.w;
            acc[3][0] += a.w * bb.x; acc[3][1] += a.w * bb.y; acc[3][2] += a.w * bb.z; acc[3][3] += a.w * bb.w;
        }
    }
    float4 bv = *(const float4*)(bias + o0 + tx * 4);
#pragma unroll
    for (int r = 0; r < 4; r++) {
        float4 o;
        float x;
        x = acc[r][0] + bv.x; o.x = x > 0.f ? x : 0.01f * x;
        x = acc[r][1] + bv.y; o.y = x > 0.f ? x : 0.01f * x;
        x = acc[r][2] + bv.z; o.z = x > 0.f ? x : 0.01f * x;
        x = acc[r][3] + bv.w; o.w = x > 0.f ? x : 0.01f * x;
        *(float4*)(out + (size_t)(m0 + ty * 4 + r) * DOUTc + o0 + tx * 4) = o;
    }
}

extern "C" void kernel_launch(void* const* d_in, const int* in_sizes, int n_in,
                              void* d_out, int out_size, void* d_ws, size_t ws_size,
                              hipStream_t stream) {
    const float* Q = (const float*)d_in[0];
    const float* keys = (const float*)d_in[1];
    const float* conv_w = (const float*)d_in[2];
    const float* lin_w = (const float*)d_in[3];
    const float* lin_b = (const float*)d_in[4];
    const int* mask = (const int*)d_in[5];

    float* out = (float*)d_out;
    float* kl = out + (size_t)Bc * Kc * DOUTc;

    float* ws = (float*)d_ws;
    float* C = ws;                               // 8,388,608 f
    float* k2 = C + (size_t)Bc * Nc * Kc;        // 4,096 f
    float* cn = k2 + (size_t)Hc * Kc;            // 8,192 f
    float* V = cn + (size_t)Bc * Kc;             // 2,097,152 f
    float* q2 = V + (size_t)Bc * Kc * Fc;        // 16,384 f
    unsigned short* Qb = (unsigned short*)(q2 + (size_t)Bc * Nc);  // 4,194,304 us
    unsigned short* Kp = Qb + (size_t)Bc * Nc * Fc;                // 1,048,576 us

    hipMemsetAsync(cn, 0, (size_t)Bc * Kc * sizeof(float), stream);
    hipMemsetAsync(kl, 0, sizeof(float), stream);

    prep_kernel<<<Bc * Nc / 4, 256, 0, stream>>>(Q, Qb, q2);
    k2_kernel<<<Hc * Kc / 256, 256, 0, stream>>>(keys, k2);
    kpack_kernel<<<Hc * Kc * Fc / (256 * 8), 256, 0, stream>>>(keys, Kp);
    cmfma_kernel<<<Bc * Nc / 16, 256, 0, stream>>>(Qb, Kp, q2, k2, conv_w, mask, C, cn);
    kl_kernel<<<1024, 256, 0, stream>>>(C, cn, kl);
    v_kernel<<<dim3(32, Bc), 256, 0, stream>>>(C, Q, V);
    out_kernel<<<dim3(128, 4), 256, 0, stream>>>(V, lin_w, lin_b, out);
}

// Round 4
// 278.464 us; speedup vs baseline: 4.2615x; 1.0551x over previous
//
#include <hip/hip_runtime.h>
#include <math.h>

#define Bc 16
#define Nc 1024
#define Fc 256
#define Hc 8
#define Kc 512
#define DOUTc 256
#define EPSc 1e-8f

typedef short v8s __attribute__((ext_vector_type(8)));
typedef float v4f __attribute__((ext_vector_type(4)));

__device__ __forceinline__ float waveReduceSum(float v) {
    v += __shfl_xor(v, 32); v += __shfl_xor(v, 16); v += __shfl_xor(v, 8);
    v += __shfl_xor(v, 4);  v += __shfl_xor(v, 2);  v += __shfl_xor(v, 1);
    return v;
}

__device__ __forceinline__ unsigned short f2bf(float f) {
    unsigned int u = __float_as_uint(f);
    u = (u + 0x7fffu + ((u >> 16) & 1u)) >> 16;   // RNE
    return (unsigned short)u;
}

// ---- prep: Q fp32 -> bf16 row-major; q2 row sums ----
__global__ __launch_bounds__(256) void prep_kernel(
    const float* __restrict__ Q, unsigned short* __restrict__ Qb,
    float* __restrict__ q2g) {
    int row = blockIdx.x * 4 + (threadIdx.x >> 6);
    int l = threadIdx.x & 63;
    const float* src = Q + (size_t)row * Fc;
    float4 v = *(const float4*)(src + l * 4);
    float s = v.x * v.x + v.y * v.y + v.z * v.z + v.w * v.w;
    ushort4 o = make_ushort4(f2bf(v.x), f2bf(v.y), f2bf(v.z), f2bf(v.w));
    *(ushort4*)(Qb + (size_t)row * Fc + l * 4) = o;
    s = waveReduceSum(s);
    if (l == 0) q2g[row] = s;
}

// ---- k2 row sums of keys ----
__global__ __launch_bounds__(256) void k2_kernel(const float* __restrict__ keys,
                                                 float* __restrict__ k2g) {
    int c = blockIdx.x * 256 + threadIdx.x;
    const float4* kp = (const float4*)(keys + (size_t)c * Fc);
    float s = 0.f;
#pragma unroll 8
    for (int i = 0; i < Fc / 4; i++) {
        float4 v = kp[i];
        s += v.x * v.x + v.y * v.y + v.z * v.z + v.w * v.w;
    }
    k2g[c] = s;
}

// ---- pack keys into MFMA B-frag streaming order (for cmfma) ----
__global__ __launch_bounds__(256) void kpack_kernel(const float* __restrict__ keys,
                                                    unsigned short* __restrict__ Kp) {
    int t = blockIdx.x * 256 + threadIdx.x;
    int lane = t & 63, ci = t >> 6;
    int ct = ci & 7, ks = (ci >> 3) & 7, wv = (ci >> 6) & 3, h = ci >> 8;
    int qd = lane >> 4, li = lane & 15;
    int col = h * 512 + wv * 128 + ct * 16 + li;
    const float* src = keys + (size_t)col * Fc + ks * 32 + qd * 8;
    float4 a = *(const float4*)src;
    float4 b = *(const float4*)(src + 4);
    *(ushort4*)(Kp + (size_t)t * 8) = make_ushort4(f2bf(a.x), f2bf(a.y), f2bf(a.z), f2bf(a.w));
    *(ushort4*)(Kp + (size_t)t * 8 + 4) = make_ushort4(f2bf(b.x), f2bf(b.y), f2bf(b.z), f2bf(b.w));
}

// ---- pack Q into MFMA B-frag order (for vmfma): Qbp[b][ft16][ns32][lane][8] ----
// chunk(b,ft,ns): lane(qd,li) holds Q[b][ns*32+qd*8+j][ft*16+li], j=0..7
__global__ __launch_bounds__(256) void qpack_kernel(const float* __restrict__ Q,
                                                    unsigned short* __restrict__ Qbp) {
    __shared__ unsigned short T2[32][66];
    int n0 = blockIdx.x * 32, f0 = blockIdx.y * 64, bb = blockIdx.z;
    int tid = threadIdx.x;
    {
        int n_l = tid >> 3, f_l = (tid & 7) * 8;
        const float* src = Q + ((size_t)(bb * Nc + n0 + n_l)) * Fc + f0 + f_l;
        float4 a = *(const float4*)src;
        float4 b = *(const float4*)(src + 4);
        T2[n_l][f_l + 0] = f2bf(a.x); T2[n_l][f_l + 1] = f2bf(a.y);
        T2[n_l][f_l + 2] = f2bf(a.z); T2[n_l][f_l + 3] = f2bf(a.w);
        T2[n_l][f_l + 4] = f2bf(b.x); T2[n_l][f_l + 5] = f2bf(b.y);
        T2[n_l][f_l + 6] = f2bf(b.z); T2[n_l][f_l + 7] = f2bf(b.w);
    }
    __syncthreads();
    int c = tid >> 6, L = tid & 63;
    int qd = L >> 4, li = L & 15;
    unsigned short o[8];
#pragma unroll
    for (int j = 0; j < 8; j++) o[j] = T2[qd * 8 + j][c * 16 + li];
    size_t idx = ((((size_t)bb * 16 + (f0 >> 4) + c) * 32 + (n0 >> 5)) * 64 + L) * 8;
    *(ushort4*)(Qbp + idx) = make_ushort4(o[0], o[1], o[2], o[3]);
    *(ushort4*)(Qbp + idx + 4) = make_ushort4(o[4], o[5], o[6], o[7]);
}

// ---- fused distance-GEMM -> cauchy -> head-norm/mix -> softmax -> C(fp32), cn, Ctp(bf16 packed) ----
__global__ __launch_bounds__(256) void cmfma_kernel(
    const unsigned short* __restrict__ Qb, const unsigned short* __restrict__ Kp,
    const float* __restrict__ q2g, const float* __restrict__ k2g,
    const float* __restrict__ conv_w, const int* __restrict__ mask,
    float* __restrict__ C, float* __restrict__ cn,
    unsigned short* __restrict__ Ctp) {
    __shared__ float redbuf[4][16];
    __shared__ short Tb[512][20];   // transposed bf16 C tile, pad 20 (8B-aligned rows)
    const int tid = threadIdx.x;
    const int wv = tid >> 6, L = tid & 63;
    const int qd = L >> 4, li = L & 15;
    const int gr0 = blockIdx.x * 16;
    const int b = gr0 >> 10;

    float q2r[4], mrow[4];
#pragma unroll
    for (int r = 0; r < 4; r++) {
        int gr = gr0 + qd * 4 + r;
        q2r[r] = q2g[gr];
        mrow[r] = (float)mask[gr];
    }

    v8s A[8];
    {
        const unsigned short* qa = Qb + (size_t)(gr0 + li) * Fc + qd * 8;
#pragma unroll
        for (int ks = 0; ks < 8; ks++) A[ks] = *(const v8s*)(qa + ks * 32);
    }

    v4f D[8], S[8];
#pragma unroll
    for (int ct = 0; ct < 8; ct++) {
        D[ct] = (v4f){0.f, 0.f, 0.f, 0.f};
        S[ct] = (v4f){0.f, 0.f, 0.f, 0.f};
    }

    const unsigned short* kwbase = Kp + (size_t)L * 8;
    v8s Bc0[8], Bn[8];
    {
        const unsigned short* p0 = kwbase + (size_t)(wv * 64) * 512;
#pragma unroll
        for (int ct = 0; ct < 8; ct++) Bc0[ct] = *(const v8s*)(p0 + ct * 512);
    }

#define KSTEP(kk, CUR, NXT)                                                        \
    do {                                                                           \
        int hn = h * 8 + (kk) + 1;                                                 \
        int hh = (hn >> 3) & 7, kn = hn & 7;                                       \
        const unsigned short* pb =                                                 \
            kwbase + (size_t)(((hh * 4 + wv) * 64 + kn * 8)) * 512;                \
        _Pragma("unroll") for (int ct = 0; ct < 8; ct++)                           \
            NXT[ct] = *(const v8s*)(pb + ct * 512);                                \
        _Pragma("unroll") for (int ct = 0; ct < 8; ct++)                           \
            D[ct] = __builtin_amdgcn_mfma_f32_16x16x32_bf16(A[kk], CUR[ct],        \
                                                            D[ct], 0, 0, 0);      \
    } while (0)

    for (int h = 0; h < Hc; ++h) {
        float wh = conv_w[h];
        KSTEP(0, Bc0, Bn); KSTEP(1, Bn, Bc0);
        KSTEP(2, Bc0, Bn); KSTEP(3, Bn, Bc0);
        KSTEP(4, Bc0, Bn); KSTEP(5, Bn, Bc0);
        KSTEP(6, Bc0, Bn); KSTEP(7, Bn, Bc0);

        float rs[4] = {0.f, 0.f, 0.f, 0.f};
#pragma unroll
        for (int ct = 0; ct < 8; ct++) {
            float k2v = k2g[h * Kc + wv * 128 + ct * 16 + li];
#pragma unroll
            for (int r = 0; r < 4; r++) {
                float d2 = fmaxf(q2r[r] + k2v - 2.f * D[ct][r], 0.f) * mrow[r];
                float t = __builtin_amdgcn_rcpf(1.f + d2);
                D[ct][r] = t;
                rs[r] += t;
            }
        }
#pragma unroll
        for (int r = 0; r < 4; r++) {
            rs[r] += __shfl_xor(rs[r], 1, 16);
            rs[r] += __shfl_xor(rs[r], 2, 16);
            rs[r] += __shfl_xor(rs[r], 4, 16);
            rs[r] += __shfl_xor(rs[r], 8, 16);
        }
        if (li == 0) {
#pragma unroll
            for (int r = 0; r < 4; r++) redbuf[wv][qd * 4 + r] = rs[r];
        }
        __syncthreads();
        float sc[4];
#pragma unroll
        for (int r = 0; r < 4; r++) {
            int rw = qd * 4 + r;
            float tot = redbuf[0][rw] + redbuf[1][rw] + redbuf[2][rw] + redbuf[3][rw];
            sc[r] = wh * __builtin_amdgcn_rcpf(tot);
        }
        __syncthreads();
#pragma unroll
        for (int ct = 0; ct < 8; ct++)
#pragma unroll
            for (int r = 0; r < 4; r++) {
                S[ct][r] += sc[r] * D[ct][r];
                D[ct][r] = 0.f;
            }
    }
#undef KSTEP

    // softmax over 512 columns
    float mx[4] = {-1e30f, -1e30f, -1e30f, -1e30f};
#pragma unroll
    for (int ct = 0; ct < 8; ct++)
#pragma unroll
        for (int r = 0; r < 4; r++) mx[r] = fmaxf(mx[r], S[ct][r]);
#pragma unroll
    for (int r = 0; r < 4; r++) {
        mx[r] = fmaxf(mx[r], __shfl_xor(mx[r], 1, 16));
        mx[r] = fmaxf(mx[r], __shfl_xor(mx[r], 2, 16));
        mx[r] = fmaxf(mx[r], __shfl_xor(mx[r], 4, 16));
        mx[r] = fmaxf(mx[r], __shfl_xor(mx[r], 8, 16));
    }
    if (li == 0) {
#pragma unroll
        for (int r = 0; r < 4; r++) redbuf[wv][qd * 4 + r] = mx[r];
    }
    __syncthreads();
#pragma unroll
    for (int r = 0; r < 4; r++) {
        int rw = qd * 4 + r;
        mx[r] = fmaxf(fmaxf(redbuf[0][rw], redbuf[1][rw]),
                      fmaxf(redbuf[2][rw], redbuf[3][rw]));
    }
    __syncthreads();
    float es[4] = {0.f, 0.f, 0.f, 0.f};
#pragma unroll
    for (int ct = 0; ct < 8; ct++)
#pragma unroll
        for (int r = 0; r < 4; r++) {
            float e = __expf(S[ct][r] - mx[r]);
            S[ct][r] = e;
            es[r] += e;
        }
#pragma unroll
    for (int r = 0; r < 4; r++) {
        es[r] += __shfl_xor(es[r], 1, 16);
        es[r] += __shfl_xor(es[r], 2, 16);
        es[r] += __shfl_xor(es[r], 4, 16);
        es[r] += __shfl_xor(es[r], 8, 16);
    }
    if (li == 0) {
#pragma unroll
        for (int r = 0; r < 4; r++) redbuf[wv][qd * 4 + r] = es[r];
    }
    __syncthreads();
    float inv[4];
#pragma unroll
    for (int r = 0; r < 4; r++) {
        int rw = qd * 4 + r;
        float tot = redbuf[0][rw] + redbuf[1][rw] + redbuf[2][rw] + redbuf[3][rw];
        inv[r] = mrow[r] / tot;
    }
#pragma unroll
    for (int ct = 0; ct < 8; ct++) {
        int k = wv * 128 + ct * 16 + li;
        float cv[4];
        float colsum = 0.f;
#pragma unroll
        for (int r = 0; r < 4; r++) {
            cv[r] = S[ct][r] * inv[r];
            C[(size_t)(gr0 + qd * 4 + r) * Kc + k] = cv[r];
            colsum += cv[r];
        }
        colsum += __shfl_xor(colsum, 16);
        colsum += __shfl_xor(colsum, 32);
        if (qd == 0) atomicAdd(&cn[b * Kc + k], colsum);
        short4 t4;
        t4.x = (short)f2bf(cv[0]); t4.y = (short)f2bf(cv[1]);
        t4.z = (short)f2bf(cv[2]); t4.w = (short)f2bf(cv[3]);
        *(short4*)&Tb[k][qd * 4] = t4;   // Tb[k][n_local]
    }
    __syncthreads();
    // coalesced-ish readout: Ctp chunk(kt,ns0): lane slot (qd', li') = Ct[kt*16+li'][ns0*32+qd'*8+j]
    {
        const int nb = gr0 & 1023;
        const int ns0 = nb >> 5;
        const int qdb = ((nb >> 4) & 1) * 2;
#pragma unroll
        for (int kk = 0; kk < 2; kk++) {
            int k = tid * 2 + kk;
            short4 s0 = *(short4*)&Tb[k][0];
            short4 s1 = *(short4*)&Tb[k][4];
            short4 s2 = *(short4*)&Tb[k][8];
            short4 s3 = *(short4*)&Tb[k][12];
            int kt = k >> 4, klo = k & 15;
            size_t cbase = (((size_t)b * 32 + kt) * 32 + ns0) * 512;  // *64 lanes *8
            short4* d0 = (short4*)(Ctp + cbase + (size_t)((qdb + 0) * 16 + klo) * 8);
            d0[0] = s0; d0[1] = s1;
            short4* d1 = (short4*)(Ctp + cbase + (size_t)((qdb + 1) * 16 + klo) * 8);
            d1[0] = s2; d1[1] = s3;
        }
    }
}

// ---- kl: one wave per row, no in-loop barriers ----
__global__ __launch_bounds__(256) void kl2_kernel(const float* __restrict__ C,
                                                  const float* __restrict__ cn,
                                                  float* __restrict__ klout) {
    __shared__ float red[4];
    int w = threadIdx.x >> 6, l = threadIdx.x & 63;
    int row = blockIdx.x * 4 + w;          // flat b*1024+n
    int b = row >> 10;
    const float* cp = C + (size_t)row * Kc + l * 8;
    const float* np = cn + b * Kc + l * 8;
    float4 c0 = *(const float4*)cp;
    float4 c1 = *(const float4*)(cp + 4);
    float4 n0 = *(const float4*)np;
    float4 n1 = *(const float4*)(np + 4);
    float p[8];
    p[0] = c0.x * c0.x / (n0.x + EPSc); p[1] = c0.y * c0.y / (n0.y + EPSc);
    p[2] = c0.z * c0.z / (n0.z + EPSc); p[3] = c0.w * c0.w / (n0.w + EPSc);
    p[4] = c1.x * c1.x / (n1.x + EPSc); p[5] = c1.y * c1.y / (n1.y + EPSc);
    p[6] = c1.z * c1.z / (n1.z + EPSc); p[7] = c1.w * c1.w / (n1.w + EPSc);
    float s = p[0] + p[1] + p[2] + p[3] + p[4] + p[5] + p[6] + p[7];
    float pn = waveReduceSum(s) + EPSc;
    float rpn = 1.0f / pn;
    float cc[8] = {c0.x, c0.y, c0.z, c0.w, c1.x, c1.y, c1.z, c1.w};
    float kacc = 0.f;
#pragma unroll
    for (int j = 0; j < 8; j++) {
        float P = p[j] * rpn;
        kacc += P * __logf((P + EPSc) / (cc[j] + EPSc));
    }
    kacc = waveReduceSum(kacc);
    if (l == 0) red[w] = kacc;
    __syncthreads();
    if (threadIdx.x == 0)
        atomicAdd(klout, 100.f * (red[0] + red[1] + red[2] + red[3]));
}

// ---- V = C^T Q via MFMA: A=Ctp chunks, B=Qbp chunks ----
__global__ __launch_bounds__(256) void vmfma_kernel(
    const unsigned short* __restrict__ Ctp, const unsigned short* __restrict__ Qbp,
    float* __restrict__ V) {
    int tid = threadIdx.x;
    int w = tid >> 6, L = tid & 63;
    int qd = L >> 4, li = L & 15;
    int wr = w >> 1, wc = w & 1;
    int bb = blockIdx.z;
    int KT0 = blockIdx.x * 4 + wr * 2;
    int FT0 = blockIdx.y * 4 + wc * 2;
    const unsigned short* pa0 = Ctp + (((size_t)bb * 32 + KT0) * 32) * 512 + L * 8;
    const unsigned short* pa1 = pa0 + (size_t)32 * 512;
    const unsigned short* pb0 = Qbp + (((size_t)bb * 16 + FT0) * 32) * 512 + L * 8;
    const unsigned short* pb1 = pb0 + (size_t)32 * 512;
    v4f acc[2][2];
#pragma unroll
    for (int a = 0; a < 2; a++)
#pragma unroll
        for (int c = 0; c < 2; c++) acc[a][c] = (v4f){0.f, 0.f, 0.f, 0.f};

    v8s A0 = *(const v8s*)pa0, A1 = *(const v8s*)pa1;
    v8s B0 = *(const v8s*)pb0, B1 = *(const v8s*)pb1;
    for (int ns = 0; ns < 32; ns++) {
        int nsn = (ns + 1) & 31;
        v8s A0n = *(const v8s*)(pa0 + nsn * 512);
        v8s A1n = *(const v8s*)(pa1 + nsn * 512);
        v8s B0n = *(const v8s*)(pb0 + nsn * 512);
        v8s B1n = *(const v8s*)(pb1 + nsn * 512);
        acc[0][0] = __builtin_amdgcn_mfma_f32_16x16x32_bf16(A0, B0, acc[0][0], 0, 0, 0);
        acc[0][1] = __builtin_amdgcn_mfma_f32_16x16x32_bf16(A0, B1, acc[0][1], 0, 0, 0);
        acc[1][0] = __builtin_amdgcn_mfma_f32_16x16x32_bf16(A1, B0, acc[1][0], 0, 0, 0);
        acc[1][1] = __builtin_amdgcn_mfma_f32_16x16x32_bf16(A1, B1, acc[1][1], 0, 0, 0);
        A0 = A0n; A1 = A1n; B0 = B0n; B1 = B1n;
    }
#pragma unroll
    for (int a = 0; a < 2; a++)
#pragma unroll
        for (int c = 0; c < 2; c++)
#pragma unroll
            for (int r = 0; r < 4; r++) {
                int k = (KT0 + a) * 16 + qd * 4 + r;
                int f = (FT0 + c) * 16 + li;
                V[((size_t)bb * Kc + k) * Fc + f] = acc[a][c][r];
            }
}

// ---- out = leaky_relu(V @ W^T + b) ----
__global__ __launch_bounds__(256) void out_kernel(const float* __restrict__ V,
                                                  const float* __restrict__ W,
                                                  const float* __restrict__ bias,
                                                  float* __restrict__ out) {
    __shared__ float Vs[16][68];
    __shared__ float Ws[16][68];
    int m0 = blockIdx.x * 64;
    int o0 = blockIdx.y * 64;
    int tid = threadIdx.x;
    int ty = tid >> 4, tx = tid & 15;
    int j = tid & 63, i4 = tid >> 6;
    float acc[4][4];
#pragma unroll
    for (int r = 0; r < 4; r++)
#pragma unroll
        for (int c = 0; c < 4; c++) acc[r][c] = 0.f;

    for (int f0 = 0; f0 < Fc; f0 += 16) {
        float4 vv = *(const float4*)(V + (size_t)(m0 + j) * Fc + f0 + i4 * 4);
        float4 wv = *(const float4*)(W + (size_t)(o0 + j) * Fc + f0 + i4 * 4);
        __syncthreads();
        Vs[i4 * 4 + 0][j] = vv.x; Vs[i4 * 4 + 1][j] = vv.y;
        Vs[i4 * 4 + 2][j] = vv.z; Vs[i4 * 4 + 3][j] = vv.w;
        Ws[i4 * 4 + 0][j] = wv.x; Ws[i4 * 4 + 1][j] = wv.y;
        Ws[i4 * 4 + 2][j] = wv.z; Ws[i4 * 4 + 3][j] = wv.w;
        __syncthreads();
#pragma unroll
        for (int i = 0; i < 16; i++) {
            float4 a = *(const float4*)&Vs[i][ty * 4];
            float4 bb = *(const float4*)&Ws[i][tx * 4];
            acc[0][0] += a.x * bb.x; acc[0][1] += a.x * bb.y; acc[0][2] += a.x * bb.z; acc[0][3] += a.x * bb.w;
            acc[1][0] += a.y * bb.x; acc[1][1] += a.y * bb.y; acc[1][2] += a.y * bb.z; acc[1][3] += a.y * bb.w;
            acc[2][0] += a.z * bb.x; acc[2][1] += a.z * bb.y; acc[2][2] += a.z * bb.z; acc[2][3] += a.z * bb.w;
            acc[3][0] += a.w * bb.x; acc[3][1] += a.w * bb.y; acc[3][2] += a.w * bb.z; acc[3][3] += a.w * bb.w;
        }
    }
    float4 bv = *(const float4*)(bias + o0 + tx * 4);
#pragma unroll
    for (int r = 0; r < 4; r++) {
        float4 o;
        float x;
        x = acc[r][0] + bv.x; o.x = x > 0.f ? x : 0.01f * x;
        x = acc[r][1] + bv.y; o.y = x > 0.f ? x : 0.01f * x;
        x = acc[r][2] + bv.z; o.z = x > 0.f ? x : 0.01f * x;
        x = acc[r][3] + bv.w; o.w = x > 0.f ? x : 0.01f * x;
        *(float4*)(out + (size_t)(m0 + ty * 4 + r) * DOUTc + o0 + tx * 4) = o;
    }
}

extern "C" void kernel_launch(void* const* d_in, const int* in_sizes, int n_in,
                              void* d_out, int out_size, void* d_ws, size_t ws_size,
                              hipStream_t stream) {
    const float* Q = (const float*)d_in[0];
    const float* keys = (const float*)d_in[1];
    const float* conv_w = (const float*)d_in[2];
    const float* lin_w = (const float*)d_in[3];
    const float* lin_b = (const float*)d_in[4];
    const int* mask = (const int*)d_in[5];

    float* out = (float*)d_out;
    float* kl = out + (size_t)Bc * Kc * DOUTc;

    float* ws = (float*)d_ws;
    float* C = ws;                                   // 8,388,608 f
    float* k2 = C + (size_t)Bc * Nc * Kc;            // 4,096 f
    float* cn = k2 + (size_t)Hc * Kc;                // 8,192 f
    float* V = cn + (size_t)Bc * Kc;                 // 2,097,152 f
    float* q2 = V + (size_t)Bc * Kc * Fc;            // 16,384 f
    unsigned short* Qb = (unsigned short*)(q2 + (size_t)Bc * Nc);  // 4,194,304 us
    unsigned short* Kp = Qb + (size_t)Bc * Nc * Fc;                // 2,097,152 us
    unsigned short* Ctp = Kp + (size_t)Hc * Kc * Fc;               // 8,388,608 us
    unsigned short* Qbp = Ctp + (size_t)Bc * Nc * Kc;              // 4,194,304 us

    hipMemsetAsync(cn, 0, (size_t)Bc * Kc * sizeof(float), stream);
    hipMemsetAsync(kl, 0, sizeof(float), stream);

    prep_kernel<<<Bc * Nc / 4, 256, 0, stream>>>(Q, Qb, q2);
    k2_kernel<<<Hc * Kc / 256, 256, 0, stream>>>(keys, k2);
    kpack_kernel<<<Hc * Kc * Fc / (256 * 8), 256, 0, stream>>>(keys, Kp);
    qpack_kernel<<<dim3(Nc / 32, Fc / 64, Bc), 256, 0, stream>>>(Q, Qbp);
    cmfma_kernel<<<Bc * Nc / 16, 256, 0, stream>>>(Qb, Kp, q2, k2, conv_w, mask, C, cn, Ctp);
    kl2_kernel<<<Bc * Nc / 4, 256, 0, stream>>>(C, cn, kl);
    vmfma_kernel<<<dim3(Kc / 64, Fc / 64, Bc), 256, 0, stream>>>(Ctp, Qbp, V);
    out_kernel<<<dim3(Bc * Kc / 64, DOUTc / 64), 256, 0, stream>>>(V, lin_w, lin_b, out);
}

// Round 5
// 209.865 us; speedup vs baseline: 5.6544x; 1.3269x over previous
//
#include <hip/hip_runtime.h>
#include <math.h>

#define Bc 16
#define Nc 1024
#define Fc 256
#define Hc 8
#define Kc 512
#define DOUTc 256
#define EPSc 1e-8f

typedef short v8s __attribute__((ext_vector_type(8)));
typedef float v4f __attribute__((ext_vector_type(4)));

__device__ __forceinline__ float waveReduceSum(float v) {
    v += __shfl_xor(v, 32); v += __shfl_xor(v, 16); v += __shfl_xor(v, 8);
    v += __shfl_xor(v, 4);  v += __shfl_xor(v, 2);  v += __shfl_xor(v, 1);
    return v;
}

__device__ __forceinline__ unsigned short f2bf(float f) {
    unsigned int u = __float_as_uint(f);
    u = (u + 0x7fffu + ((u >> 16) & 1u)) >> 16;   // RNE
    return (unsigned short)u;
}

// ================= fused preprocessing =================
// ranges: [0,4096)  Q->Qb + q2        (4 rows/block)
//         [4096,5120) k2              (4 key rows/block)
//         [5120,5632) kpack -> Kp     (B-frag order for cmfma)
//         [5632,7680) qpack -> Qbp    (B-frag order for vmfma)
//         [7680,7712) wpack -> Wp     (B-frag order for ofma)
__global__ __launch_bounds__(256) void prep_all(
    const float* __restrict__ Q, const float* __restrict__ keys,
    const float* __restrict__ lin_w,
    unsigned short* __restrict__ Qb, float* __restrict__ q2g,
    float* __restrict__ k2g, unsigned short* __restrict__ Kp,
    unsigned short* __restrict__ Qbp, unsigned short* __restrict__ Wp) {
    __shared__ unsigned short T2[32][66];
    const int bx = blockIdx.x;
    const int tid = threadIdx.x;
    if (bx < 4096) {
        int row = bx * 4 + (tid >> 6);
        int l = tid & 63;
        float4 v = *(const float4*)(Q + (size_t)row * Fc + l * 4);
        float s = v.x * v.x + v.y * v.y + v.z * v.z + v.w * v.w;
        *(ushort4*)(Qb + (size_t)row * Fc + l * 4) =
            make_ushort4(f2bf(v.x), f2bf(v.y), f2bf(v.z), f2bf(v.w));
        s = waveReduceSum(s);
        if (l == 0) q2g[row] = s;
    } else if (bx < 5120) {
        int row = (bx - 4096) * 4 + (tid >> 6);
        int l = tid & 63;
        float4 v = *(const float4*)(keys + (size_t)row * Fc + l * 4);
        float s = v.x * v.x + v.y * v.y + v.z * v.z + v.w * v.w;
        s = waveReduceSum(s);
        if (l == 0) k2g[row] = s;
    } else if (bx < 5632) {
        int t = (bx - 5120) * 256 + tid;
        int lane = t & 63, ci = t >> 6;
        int ct = ci & 7, ks = (ci >> 3) & 7, wv = (ci >> 6) & 3, h = ci >> 8;
        int qd = lane >> 4, li = lane & 15;
        int col = h * 512 + wv * 128 + ct * 16 + li;
        const float* src = keys + (size_t)col * Fc + ks * 32 + qd * 8;
        float4 a = *(const float4*)src;
        float4 b = *(const float4*)(src + 4);
        *(ushort4*)(Kp + (size_t)t * 8) = make_ushort4(f2bf(a.x), f2bf(a.y), f2bf(a.z), f2bf(a.w));
        *(ushort4*)(Kp + (size_t)t * 8 + 4) = make_ushort4(f2bf(b.x), f2bf(b.y), f2bf(b.z), f2bf(b.w));
    } else if (bx < 7680) {
        int i = bx - 5632;
        int n0 = (i & 31) * 32, f0 = ((i >> 5) & 3) * 64, bb = i >> 7;
        {
            int n_l = tid >> 3, f_l = (tid & 7) * 8;
            const float* src = Q + ((size_t)(bb * Nc + n0 + n_l)) * Fc + f0 + f_l;
            float4 a = *(const float4*)src;
            float4 b = *(const float4*)(src + 4);
            T2[n_l][f_l + 0] = f2bf(a.x); T2[n_l][f_l + 1] = f2bf(a.y);
            T2[n_l][f_l + 2] = f2bf(a.z); T2[n_l][f_l + 3] = f2bf(a.w);
            T2[n_l][f_l + 4] = f2bf(b.x); T2[n_l][f_l + 5] = f2bf(b.y);
            T2[n_l][f_l + 6] = f2bf(b.z); T2[n_l][f_l + 7] = f2bf(b.w);
        }
        __syncthreads();
        int c = tid >> 6, L = tid & 63;
        int qd = L >> 4, li = L & 15;
        unsigned short o[8];
#pragma unroll
        for (int j = 0; j < 8; j++) o[j] = T2[qd * 8 + j][c * 16 + li];
        size_t idx = ((((size_t)bb * 16 + (f0 >> 4) + c) * 32 + (n0 >> 5)) * 64 + L) * 8;
        *(ushort4*)(Qbp + idx) = make_ushort4(o[0], o[1], o[2], o[3]);
        *(ushort4*)(Qbp + idx + 4) = make_ushort4(o[4], o[5], o[6], o[7]);
    } else {
        int t = (bx - 7680) * 256 + tid;   // 8192 threads, 8 elems each
        int lane = t & 63, ci = t >> 6;    // ci 0..127
        int ot = ci >> 3, fs = ci & 7;
        int qd = lane >> 4, li = lane & 15;
        const float* src = lin_w + (size_t)(ot * 16 + li) * Fc + fs * 32 + qd * 8;
        float4 a = *(const float4*)src;
        float4 b = *(const float4*)(src + 4);
        *(ushort4*)(Wp + (size_t)t * 8) = make_ushort4(f2bf(a.x), f2bf(a.y), f2bf(a.z), f2bf(a.w));
        *(ushort4*)(Wp + (size_t)t * 8 + 4) = make_ushort4(f2bf(b.x), f2bf(b.y), f2bf(b.z), f2bf(b.w));
    }
}

// ====== fused distance-GEMM (32 rows/block) -> cauchy -> head-norm/mix -> softmax -> C, cn, Ctp ======
__global__ __launch_bounds__(256, 1) void cmfma_kernel(
    const unsigned short* __restrict__ Qb, const unsigned short* __restrict__ Kp,
    const float* __restrict__ q2g, const float* __restrict__ k2g,
    const float* __restrict__ conv_w, const int* __restrict__ mask,
    float* __restrict__ C, float* __restrict__ cn,
    unsigned short* __restrict__ Ctp) {
    __shared__ float redbuf[4][32];
    __shared__ short Tb[512][36];   // [k][n_local], pad 36 (72 B rows)
    const int tid = threadIdx.x;
    const int wv = tid >> 6, L = tid & 63;
    const int qd = L >> 4, li = L & 15;
    const int gr0 = blockIdx.x * 32;   // flat row over B*N, 32 rows/block
    const int b = gr0 >> 10;

    float q2r[2][4], mrow[2][4];
#pragma unroll
    for (int s = 0; s < 2; s++)
#pragma unroll
        for (int r = 0; r < 4; r++) {
            int gr = gr0 + s * 16 + qd * 4 + r;
            q2r[s][r] = q2g[gr];
            mrow[s][r] = (float)mask[gr];
        }

    v8s A[2][8];
#pragma unroll
    for (int s = 0; s < 2; s++) {
        const unsigned short* qa = Qb + (size_t)(gr0 + s * 16 + li) * Fc + qd * 8;
#pragma unroll
        for (int ks = 0; ks < 8; ks++) A[s][ks] = *(const v8s*)(qa + ks * 32);
    }

    v4f D[2][8], S[2][8];
#pragma unroll
    for (int s = 0; s < 2; s++)
#pragma unroll
        for (int ct = 0; ct < 8; ct++) {
            D[s][ct] = (v4f){0.f, 0.f, 0.f, 0.f};
            S[s][ct] = (v4f){0.f, 0.f, 0.f, 0.f};
        }

    const unsigned short* kwbase = Kp + (size_t)L * 8;
    v8s Bc0[8], Bn[8];
    {
        const unsigned short* p0 = kwbase + (size_t)(wv * 64) * 512;
#pragma unroll
        for (int ct = 0; ct < 8; ct++) Bc0[ct] = *(const v8s*)(p0 + ct * 512);
    }

#define KSTEP(kk, CUR, NXT)                                                        \
    do {                                                                           \
        int hn = h * 8 + (kk) + 1;                                                 \
        int hh = (hn >> 3) & 7, kn = hn & 7;                                       \
        const unsigned short* pb =                                                 \
            kwbase + (size_t)(((hh * 4 + wv) * 64 + kn * 8)) * 512;                \
        _Pragma("unroll") for (int ct = 0; ct < 8; ct++)                           \
            NXT[ct] = *(const v8s*)(pb + ct * 512);                                \
        _Pragma("unroll") for (int ct = 0; ct < 8; ct++)                           \
            D[0][ct] = __builtin_amdgcn_mfma_f32_16x16x32_bf16(A[0][kk], CUR[ct],  \
                                                               D[0][ct], 0, 0, 0);\
        _Pragma("unroll") for (int ct = 0; ct < 8; ct++)                           \
            D[1][ct] = __builtin_amdgcn_mfma_f32_16x16x32_bf16(A[1][kk], CUR[ct],  \
                                                               D[1][ct], 0, 0, 0);\
    } while (0)

    for (int h = 0; h < Hc; ++h) {
        float wh = conv_w[h];
        KSTEP(0, Bc0, Bn); KSTEP(1, Bn, Bc0);
        KSTEP(2, Bc0, Bn); KSTEP(3, Bn, Bc0);
        KSTEP(4, Bc0, Bn); KSTEP(5, Bn, Bc0);
        KSTEP(6, Bc0, Bn); KSTEP(7, Bn, Bc0);

        float rs[2][4] = {{0.f, 0.f, 0.f, 0.f}, {0.f, 0.f, 0.f, 0.f}};
#pragma unroll
        for (int ct = 0; ct < 8; ct++) {
            float k2v = k2g[h * Kc + wv * 128 + ct * 16 + li];
#pragma unroll
            for (int s = 0; s < 2; s++)
#pragma unroll
                for (int r = 0; r < 4; r++) {
                    float d2 = fmaxf(q2r[s][r] + k2v - 2.f * D[s][ct][r], 0.f) * mrow[s][r];
                    float t = __builtin_amdgcn_rcpf(1.f + d2);
                    D[s][ct][r] = t;
                    rs[s][r] += t;
                }
        }
#pragma unroll
        for (int s = 0; s < 2; s++)
#pragma unroll
            for (int r = 0; r < 4; r++) {
                rs[s][r] += __shfl_xor(rs[s][r], 1, 16);
                rs[s][r] += __shfl_xor(rs[s][r], 2, 16);
                rs[s][r] += __shfl_xor(rs[s][r], 4, 16);
                rs[s][r] += __shfl_xor(rs[s][r], 8, 16);
            }
        if (li == 0) {
#pragma unroll
            for (int s = 0; s < 2; s++)
#pragma unroll
                for (int r = 0; r < 4; r++) redbuf[wv][s * 16 + qd * 4 + r] = rs[s][r];
        }
        __syncthreads();
        float sc[2][4];
#pragma unroll
        for (int s = 0; s < 2; s++)
#pragma unroll
            for (int r = 0; r < 4; r++) {
                int rw = s * 16 + qd * 4 + r;
                float tot = redbuf[0][rw] + redbuf[1][rw] + redbuf[2][rw] + redbuf[3][rw];
                sc[s][r] = wh * __builtin_amdgcn_rcpf(tot);
            }
        __syncthreads();
#pragma unroll
        for (int s = 0; s < 2; s++)
#pragma unroll
            for (int ct = 0; ct < 8; ct++)
#pragma unroll
                for (int r = 0; r < 4; r++) {
                    S[s][ct][r] += sc[s][r] * D[s][ct][r];
                    D[s][ct][r] = 0.f;
                }
    }
#undef KSTEP

    // softmax over 512 columns (per row)
    float mx[2][4] = {{-1e30f, -1e30f, -1e30f, -1e30f}, {-1e30f, -1e30f, -1e30f, -1e30f}};
#pragma unroll
    for (int s = 0; s < 2; s++)
#pragma unroll
        for (int ct = 0; ct < 8; ct++)
#pragma unroll
            for (int r = 0; r < 4; r++) mx[s][r] = fmaxf(mx[s][r], S[s][ct][r]);
#pragma unroll
    for (int s = 0; s < 2; s++)
#pragma unroll
        for (int r = 0; r < 4; r++) {
            mx[s][r] = fmaxf(mx[s][r], __shfl_xor(mx[s][r], 1, 16));
            mx[s][r] = fmaxf(mx[s][r], __shfl_xor(mx[s][r], 2, 16));
            mx[s][r] = fmaxf(mx[s][r], __shfl_xor(mx[s][r], 4, 16));
            mx[s][r] = fmaxf(mx[s][r], __shfl_xor(mx[s][r], 8, 16));
        }
    if (li == 0) {
#pragma unroll
        for (int s = 0; s < 2; s++)
#pragma unroll
            for (int r = 0; r < 4; r++) redbuf[wv][s * 16 + qd * 4 + r] = mx[s][r];
    }
    __syncthreads();
#pragma unroll
    for (int s = 0; s < 2; s++)
#pragma unroll
        for (int r = 0; r < 4; r++) {
            int rw = s * 16 + qd * 4 + r;
            mx[s][r] = fmaxf(fmaxf(redbuf[0][rw], redbuf[1][rw]),
                             fmaxf(redbuf[2][rw], redbuf[3][rw]));
        }
    __syncthreads();
    float es[2][4] = {{0.f, 0.f, 0.f, 0.f}, {0.f, 0.f, 0.f, 0.f}};
#pragma unroll
    for (int s = 0; s < 2; s++)
#pragma unroll
        for (int ct = 0; ct < 8; ct++)
#pragma unroll
            for (int r = 0; r < 4; r++) {
                float e = __expf(S[s][ct][r] - mx[s][r]);
                S[s][ct][r] = e;
                es[s][r] += e;
            }
#pragma unroll
    for (int s = 0; s < 2; s++)
#pragma unroll
        for (int r = 0; r < 4; r++) {
            es[s][r] += __shfl_xor(es[s][r], 1, 16);
            es[s][r] += __shfl_xor(es[s][r], 2, 16);
            es[s][r] += __shfl_xor(es[s][r], 4, 16);
            es[s][r] += __shfl_xor(es[s][r], 8, 16);
        }
    if (li == 0) {
#pragma unroll
        for (int s = 0; s < 2; s++)
#pragma unroll
            for (int r = 0; r < 4; r++) redbuf[wv][s * 16 + qd * 4 + r] = es[s][r];
    }
    __syncthreads();
    float inv[2][4];
#pragma unroll
    for (int s = 0; s < 2; s++)
#pragma unroll
        for (int r = 0; r < 4; r++) {
            int rw = s * 16 + qd * 4 + r;
            float tot = redbuf[0][rw] + redbuf[1][rw] + redbuf[2][rw] + redbuf[3][rw];
            inv[s][r] = mrow[s][r] / tot;
        }
#pragma unroll
    for (int ct = 0; ct < 8; ct++) {
        int k = wv * 128 + ct * 16 + li;
        float colsum = 0.f;
#pragma unroll
        for (int s = 0; s < 2; s++) {
            float cv[4];
#pragma unroll
            for (int r = 0; r < 4; r++) {
                cv[r] = S[s][ct][r] * inv[s][r];
                C[(size_t)(gr0 + s * 16 + qd * 4 + r) * Kc + k] = cv[r];
                colsum += cv[r];
            }
            short4 t4;
            t4.x = (short)f2bf(cv[0]); t4.y = (short)f2bf(cv[1]);
            t4.z = (short)f2bf(cv[2]); t4.w = (short)f2bf(cv[3]);
            *(short4*)&Tb[k][s * 16 + qd * 4] = t4;
        }
        colsum += __shfl_xor(colsum, 16);
        colsum += __shfl_xor(colsum, 32);
        if (qd == 0) atomicAdd(&cn[b * Kc + k], colsum);
    }
    __syncthreads();
    // pack bf16 C^T chunks: block covers exactly one ns-chunk (32 rows)
    {
        const int ns0 = (gr0 & 1023) >> 5;
#pragma unroll
        for (int kk = 0; kk < 2; kk++) {
            int k = tid * 2 + kk;
            int kt = k >> 4, klo = k & 15;
            size_t cbase = (((size_t)b * 32 + kt) * 32 + ns0) * 512;
#pragma unroll
            for (int q2i = 0; q2i < 4; q2i++) {
                short4 lo = *(short4*)&Tb[k][q2i * 8];
                short4 hi = *(short4*)&Tb[k][q2i * 8 + 4];
                short4* d = (short4*)(Ctp + cbase + (size_t)(q2i * 16 + klo) * 8);
                d[0] = lo; d[1] = hi;
            }
        }
    }
}

// ---- kl: 16 rows/block, 1 atomic/block ----
__global__ __launch_bounds__(256) void kl2_kernel(const float* __restrict__ C,
                                                  const float* __restrict__ cn,
                                                  float* __restrict__ klout) {
    __shared__ float red[4];
    int w = threadIdx.x >> 6, l = threadIdx.x & 63;
    float kacc = 0.f;
#pragma unroll
    for (int rr = 0; rr < 4; rr++) {
        int row = blockIdx.x * 16 + w * 4 + rr;
        int b = row >> 10;
        const float* cp = C + (size_t)row * Kc + l * 8;
        const float* np = cn + b * Kc + l * 8;
        float4 c0 = *(const float4*)cp;
        float4 c1 = *(const float4*)(cp + 4);
        float4 n0 = *(const float4*)np;
        float4 n1 = *(const float4*)(np + 4);
        float p[8];
        p[0] = c0.x * c0.x / (n0.x + EPSc); p[1] = c0.y * c0.y / (n0.y + EPSc);
        p[2] = c0.z * c0.z / (n0.z + EPSc); p[3] = c0.w * c0.w / (n0.w + EPSc);
        p[4] = c1.x * c1.x / (n1.x + EPSc); p[5] = c1.y * c1.y / (n1.y + EPSc);
        p[6] = c1.z * c1.z / (n1.z + EPSc); p[7] = c1.w * c1.w / (n1.w + EPSc);
        float s = p[0] + p[1] + p[2] + p[3] + p[4] + p[5] + p[6] + p[7];
        float pn = waveReduceSum(s) + EPSc;
        float rpn = 1.0f / pn;
        float cc[8] = {c0.x, c0.y, c0.z, c0.w, c1.x, c1.y, c1.z, c1.w};
#pragma unroll
        for (int j = 0; j < 8; j++) {
            float P = p[j] * rpn;
            kacc += P * __logf((P + EPSc) / (cc[j] + EPSc));
        }
    }
    kacc = waveReduceSum(kacc);
    if (l == 0) red[w] = kacc;
    __syncthreads();
    if (threadIdx.x == 0)
        atomicAdd(klout, 100.f * (red[0] + red[1] + red[2] + red[3]));
}

// ---- V = C^T Q via MFMA; epilogue packs V into bf16 A-frag layout Vp ----
__global__ __launch_bounds__(256) void vmfma_kernel(
    const unsigned short* __restrict__ Ctp, const unsigned short* __restrict__ Qbp,
    unsigned short* __restrict__ Vp) {
    __shared__ short Vt[64][76];
    int tid = threadIdx.x;
    int w = tid >> 6, L = tid & 63;
    int qd = L >> 4, li = L & 15;
    int wr = w >> 1, wc = w & 1;
    int bb = blockIdx.z;
    int KT0 = blockIdx.x * 4 + wr * 2;
    int FT0 = blockIdx.y * 4 + wc * 2;
    const unsigned short* pa0 = Ctp + (((size_t)bb * 32 + KT0) * 32) * 512 + L * 8;
    const unsigned short* pa1 = pa0 + (size_t)32 * 512;
    const unsigned short* pb0 = Qbp + (((size_t)bb * 16 + FT0) * 32) * 512 + L * 8;
    const unsigned short* pb1 = pb0 + (size_t)32 * 512;
    v4f acc[2][2];
#pragma unroll
    for (int a = 0; a < 2; a++)
#pragma unroll
        for (int c = 0; c < 2; c++) acc[a][c] = (v4f){0.f, 0.f, 0.f, 0.f};

    v8s A0 = *(const v8s*)pa0, A1 = *(const v8s*)pa1;
    v8s B0 = *(const v8s*)pb0, B1 = *(const v8s*)pb1;
    for (int ns = 0; ns < 32; ns++) {
        int nsn = (ns + 1) & 31;
        v8s A0n = *(const v8s*)(pa0 + nsn * 512);
        v8s A1n = *(const v8s*)(pa1 + nsn * 512);
        v8s B0n = *(const v8s*)(pb0 + nsn * 512);
        v8s B1n = *(const v8s*)(pb1 + nsn * 512);
        acc[0][0] = __builtin_amdgcn_mfma_f32_16x16x32_bf16(A0, B0, acc[0][0], 0, 0, 0);
        acc[0][1] = __builtin_amdgcn_mfma_f32_16x16x32_bf16(A0, B1, acc[0][1], 0, 0, 0);
        acc[1][0] = __builtin_amdgcn_mfma_f32_16x16x32_bf16(A1, B0, acc[1][0], 0, 0, 0);
        acc[1][1] = __builtin_amdgcn_mfma_f32_16x16x32_bf16(A1, B1, acc[1][1], 0, 0, 0);
        A0 = A0n; A1 = A1n; B0 = B0n; B1 = B1n;
    }
    // stage bf16 V tile (64 k x 64 f) in LDS
#pragma unroll
    for (int a = 0; a < 2; a++)
#pragma unroll
        for (int c = 0; c < 2; c++)
#pragma unroll
            for (int r = 0; r < 4; r++)
                Vt[(wr * 2 + a) * 16 + qd * 4 + r][(wc * 2 + c) * 16 + li] =
                    (short)f2bf(acc[a][c][r]);
    __syncthreads();
    // pack into A-frag chunks: chunk(mt, fs): lane(qd',li') = V[mt*16+li'][fs*32+qd'*8+j]
    {
        int ci = tid >> 5, s5 = tid & 31;
        int mtl = ci >> 1, fsl = ci & 1;
        size_t mt_g = (size_t)bb * 32 + blockIdx.x * 4 + mtl;
        size_t fs_g = (size_t)blockIdx.y * 2 + fsl;
#pragma unroll
        for (int half = 0; half < 2; half++) {
            int L2 = s5 + half * 32;
            int qd2 = L2 >> 4, li2 = L2 & 15;
            short4 x0 = *(short4*)&Vt[mtl * 16 + li2][fsl * 32 + qd2 * 8];
            short4 x1 = *(short4*)&Vt[mtl * 16 + li2][fsl * 32 + qd2 * 8 + 4];
            short4* d = (short4*)(Vp + ((mt_g * 8 + fs_g) * 64 + L2) * 8);
            d[0] = x0; d[1] = x1;
        }
    }
}

// ---- out = leaky_relu(Vp @ Wp^T + b) via MFMA ----
__global__ __launch_bounds__(256) void ofma_kernel(
    const unsigned short* __restrict__ Vp, const unsigned short* __restrict__ Wp,
    const float* __restrict__ bias, float* __restrict__ out) {
    int tid = threadIdx.x;
    int w = tid >> 6, L = tid & 63;
    int qd = L >> 4, li = L & 15;
    int wr = w >> 1, wc = w & 1;
    int MT0 = blockIdx.x * 4 + wr * 2;   // m-tiles over 8192 rows (512 tiles)
    int OT0 = blockIdx.y * 4 + wc * 2;   // o-tiles over 256 (16 tiles)
    const unsigned short* pa0 = Vp + ((size_t)MT0 * 8) * 512 + L * 8;
    const unsigned short* pa1 = pa0 + (size_t)8 * 512;
    const unsigned short* pb0 = Wp + ((size_t)OT0 * 8) * 512 + L * 8;
    const unsigned short* pb1 = pb0 + (size_t)8 * 512;
    v4f acc[2][2];
#pragma unroll
    for (int a = 0; a < 2; a++)
#pragma unroll
        for (int c = 0; c < 2; c++) acc[a][c] = (v4f){0.f, 0.f, 0.f, 0.f};
#pragma unroll
    for (int fs = 0; fs < 8; fs++) {
        v8s A0 = *(const v8s*)(pa0 + fs * 512);
        v8s A1 = *(const v8s*)(pa1 + fs * 512);
        v8s B0 = *(const v8s*)(pb0 + fs * 512);
        v8s B1 = *(const v8s*)(pb1 + fs * 512);
        acc[0][0] = __builtin_amdgcn_mfma_f32_16x16x32_bf16(A0, B0, acc[0][0], 0, 0, 0);
        acc[0][1] = __builtin_amdgcn_mfma_f32_16x16x32_bf16(A0, B1, acc[0][1], 0, 0, 0);
        acc[1][0] = __builtin_amdgcn_mfma_f32_16x16x32_bf16(A1, B0, acc[1][0], 0, 0, 0);
        acc[1][1] = __builtin_amdgcn_mfma_f32_16x16x32_bf16(A1, B1, acc[1][1], 0, 0, 0);
    }
#pragma unroll
    for (int c = 0; c < 2; c++) {
        float bv = bias[(OT0 + c) * 16 + li];
#pragma unroll
        for (int a = 0; a < 2; a++)
#pragma unroll
            for (int r = 0; r < 4; r++) {
                int m = (MT0 + a) * 16 + qd * 4 + r;
                int o = (OT0 + c) * 16 + li;
                float x = acc[a][c][r] + bv;
                out[(size_t)m * DOUTc + o] = x > 0.f ? x : 0.01f * x;
            }
    }
}

extern "C" void kernel_launch(void* const* d_in, const int* in_sizes, int n_in,
                              void* d_out, int out_size, void* d_ws, size_t ws_size,
                              hipStream_t stream) {
    const float* Q = (const float*)d_in[0];
    const float* keys = (const float*)d_in[1];
    const float* conv_w = (const float*)d_in[2];
    const float* lin_w = (const float*)d_in[3];
    const float* lin_b = (const float*)d_in[4];
    const int* mask = (const int*)d_in[5];

    float* out = (float*)d_out;
    float* kl = out + (size_t)Bc * Kc * DOUTc;

    float* ws = (float*)d_ws;
    float* C = ws;                                   // 8,388,608 f
    float* k2 = C + (size_t)Bc * Nc * Kc;            // 4,096 f
    float* cn = k2 + (size_t)Hc * Kc;                // 8,192 f
    float* q2 = cn + (size_t)Bc * Kc;                // 16,384 f
    unsigned short* Qb = (unsigned short*)(q2 + (size_t)Bc * Nc);  // 4,194,304 us
    unsigned short* Kp = Qb + (size_t)Bc * Nc * Fc;                // 1,048,576 us
    unsigned short* Ctp = Kp + (size_t)Hc * Kc * Fc;               // 8,388,608 us
    unsigned short* Qbp = Ctp + (size_t)Bc * Nc * Kc;              // 4,194,304 us
    unsigned short* Vp = Qbp + (size_t)Bc * Nc * Fc;               // 2,097,152 us
    unsigned short* Wp = Vp + (size_t)Bc * Kc * Fc;                // 65,536 us

    hipMemsetAsync(cn, 0, (size_t)Bc * Kc * sizeof(float), stream);
    hipMemsetAsync(kl, 0, sizeof(float), stream);

    prep_all<<<7712, 256, 0, stream>>>(Q, keys, lin_w, Qb, q2, k2, Kp, Qbp, Wp);
    cmfma_kernel<<<Bc * Nc / 32, 256, 0, stream>>>(Qb, Kp, q2, k2, conv_w, mask, C, cn, Ctp);
    kl2_kernel<<<Bc * Nc / 16, 256, 0, stream>>>(C, cn, kl);
    vmfma_kernel<<<dim3(Kc / 64, Fc / 64, Bc), 256, 0, stream>>>(Ctp, Qbp, Vp);
    ofma_kernel<<<dim3(Bc * Kc / 64, DOUTc / 64), 256, 0, stream>>>(Vp, Wp, lin_b, out);
}

// Round 6
// 192.604 us; speedup vs baseline: 6.1612x; 1.0896x over previous
//
#include <hip/hip_runtime.h>
#include <math.h>

#define Bc 16
#define Nc 1024
#define Fc 256
#define Hc 8
#define Kc 512
#define DOUTc 256
#define EPSc 1e-8f

typedef short v8s __attribute__((ext_vector_type(8)));
typedef float v4f __attribute__((ext_vector_type(4)));

__device__ __forceinline__ float waveReduceSum(float v) {
    v += __shfl_xor(v, 32); v += __shfl_xor(v, 16); v += __shfl_xor(v, 8);
    v += __shfl_xor(v, 4);  v += __shfl_xor(v, 2);  v += __shfl_xor(v, 1);
    return v;
}

__device__ __forceinline__ unsigned short f2bf(float f) {
    unsigned int u = __float_as_uint(f);
    u = (u + 0x7fffu + ((u >> 16) & 1u)) >> 16;   // RNE
    return (unsigned short)u;
}

// CK-style LDS-only barrier: drains lgkmcnt but leaves global loads in flight.
__device__ __forceinline__ void lds_barrier() {
    __builtin_amdgcn_s_waitcnt(0xC07F);   // lgkmcnt(0), vmcnt=63 (no wait), expcnt=7
    __builtin_amdgcn_s_barrier();
}

// ================= fused preprocessing =================
// ranges: [0,1024)    k2 row sums        (4 key rows/block)
//         [1024,1536) kpack -> Kp        (B-frag order for cmfma)
//         [1536,3584) qpack -> Qbp       (B-frag order for vmfma)
//         [3584,3616) wpack -> Wp        (B-frag order for ofma)
//         [3616,3618) zero cn + kl
__global__ __launch_bounds__(256) void prep_all(
    const float* __restrict__ Q, const float* __restrict__ keys,
    const float* __restrict__ lin_w,
    float* __restrict__ k2g, unsigned short* __restrict__ Kp,
    unsigned short* __restrict__ Qbp, unsigned short* __restrict__ Wp,
    float* __restrict__ cn, float* __restrict__ klout) {
    __shared__ unsigned short T2[32][66];
    const int bx = blockIdx.x;
    const int tid = threadIdx.x;
    if (bx < 1024) {
        int row = bx * 4 + (tid >> 6);
        int l = tid & 63;
        float4 v = *(const float4*)(keys + (size_t)row * Fc + l * 4);
        float s = v.x * v.x + v.y * v.y + v.z * v.z + v.w * v.w;
        s = waveReduceSum(s);
        if (l == 0) k2g[row] = s;
    } else if (bx < 1536) {
        int t = (bx - 1024) * 256 + tid;
        int lane = t & 63, ci = t >> 6;
        int ct = ci & 7, ks = (ci >> 3) & 7, wv = (ci >> 6) & 3, h = ci >> 8;
        int qd = lane >> 4, li = lane & 15;
        int col = h * 512 + wv * 128 + ct * 16 + li;
        const float* src = keys + (size_t)col * Fc + ks * 32 + qd * 8;
        float4 a = *(const float4*)src;
        float4 b = *(const float4*)(src + 4);
        *(ushort4*)(Kp + (size_t)t * 8) = make_ushort4(f2bf(a.x), f2bf(a.y), f2bf(a.z), f2bf(a.w));
        *(ushort4*)(Kp + (size_t)t * 8 + 4) = make_ushort4(f2bf(b.x), f2bf(b.y), f2bf(b.z), f2bf(b.w));
    } else if (bx < 3584) {
        int i = bx - 1536;
        int n0 = (i & 31) * 32, f0 = ((i >> 5) & 3) * 64, bb = i >> 7;
        {
            int n_l = tid >> 3, f_l = (tid & 7) * 8;
            const float* src = Q + ((size_t)(bb * Nc + n0 + n_l)) * Fc + f0 + f_l;
            float4 a = *(const float4*)src;
            float4 b = *(const float4*)(src + 4);
            T2[n_l][f_l + 0] = f2bf(a.x); T2[n_l][f_l + 1] = f2bf(a.y);
            T2[n_l][f_l + 2] = f2bf(a.z); T2[n_l][f_l + 3] = f2bf(a.w);
            T2[n_l][f_l + 4] = f2bf(b.x); T2[n_l][f_l + 5] = f2bf(b.y);
            T2[n_l][f_l + 6] = f2bf(b.z); T2[n_l][f_l + 7] = f2bf(b.w);
        }
        __syncthreads();
        int c = tid >> 6, L = tid & 63;
        int qd = L >> 4, li = L & 15;
        unsigned short o[8];
#pragma unroll
        for (int j = 0; j < 8; j++) o[j] = T2[qd * 8 + j][c * 16 + li];
        size_t idx = ((((size_t)bb * 16 + (f0 >> 4) + c) * 32 + (n0 >> 5)) * 64 + L) * 8;
        *(ushort4*)(Qbp + idx) = make_ushort4(o[0], o[1], o[2], o[3]);
        *(ushort4*)(Qbp + idx + 4) = make_ushort4(o[4], o[5], o[6], o[7]);
    } else if (bx < 3616) {
        int t = (bx - 3584) * 256 + tid;
        int lane = t & 63, ci = t >> 6;
        int ot = ci >> 3, fs = ci & 7;
        int qd = lane >> 4, li = lane & 15;
        const float* src = lin_w + (size_t)(ot * 16 + li) * Fc + fs * 32 + qd * 8;
        float4 a = *(const float4*)src;
        float4 b = *(const float4*)(src + 4);
        *(ushort4*)(Wp + (size_t)t * 8) = make_ushort4(f2bf(a.x), f2bf(a.y), f2bf(a.z), f2bf(a.w));
        *(ushort4*)(Wp + (size_t)t * 8 + 4) = make_ushort4(f2bf(b.x), f2bf(b.y), f2bf(b.z), f2bf(b.w));
    } else {
        int i = (bx - 3616) * 256 + tid;   // 512 threads x 16 floats = 8192
        float4 z = make_float4(0.f, 0.f, 0.f, 0.f);
        float4* d = (float4*)(cn + (size_t)i * 16);
        d[0] = z; d[1] = z; d[2] = z; d[3] = z;
        if (bx == 3616 && tid == 0) *klout = 0.f;
    }
}

// ====== fused distance-GEMM (32 rows/block) with light barriers ======
__global__ __launch_bounds__(256, 1) void cmfma_kernel(
    const float* __restrict__ Q, const unsigned short* __restrict__ Kp,
    const float* __restrict__ k2g, const float* __restrict__ conv_w,
    const int* __restrict__ mask, float* __restrict__ C,
    float* __restrict__ cn, unsigned short* __restrict__ Ctp) {
    __shared__ float k2s[Hc * Kc];          // 16 KB
    __shared__ float q2s[32];
    __shared__ float msh[32];
    __shared__ float redb[Hc][4][32];       // 4 KB, dedicated slot per head
    __shared__ float mslot[4][32];
    __shared__ float eslot[4][32];
    __shared__ short Tb[512][36];           // 36 KB
    const int tid = threadIdx.x;
    const int wv = tid >> 6, L = tid & 63;
    const int qd = L >> 4, li = L & 15;
    const int gr0 = blockIdx.x * 32;
    const int b = gr0 >> 10;

    // ---- build A-frags inline from fp32 Q (bf16 RNE) + fp32 q2 ----
    v8s A[2][8];
    {
        float q2part[2] = {0.f, 0.f};
#pragma unroll
        for (int s = 0; s < 2; s++) {
            const float* qrow = Q + (size_t)(gr0 + s * 16 + li) * Fc + qd * 8;
#pragma unroll
            for (int ks = 0; ks < 8; ks++) {
                float4 a = *(const float4*)(qrow + ks * 32);
                float4 bq = *(const float4*)(qrow + ks * 32 + 4);
                v8s f;
                f[0] = (short)f2bf(a.x);  f[1] = (short)f2bf(a.y);
                f[2] = (short)f2bf(a.z);  f[3] = (short)f2bf(a.w);
                f[4] = (short)f2bf(bq.x); f[5] = (short)f2bf(bq.y);
                f[6] = (short)f2bf(bq.z); f[7] = (short)f2bf(bq.w);
                A[s][ks] = f;
                q2part[s] += a.x * a.x + a.y * a.y + a.z * a.z + a.w * a.w +
                             bq.x * bq.x + bq.y * bq.y + bq.z * bq.z + bq.w * bq.w;
            }
            q2part[s] += __shfl_xor(q2part[s], 16);
            q2part[s] += __shfl_xor(q2part[s], 32);
            if (qd == 0 && wv == 0) q2s[s * 16 + li] = q2part[s];
        }
    }
    if (tid < 32) msh[tid] = (float)mask[gr0 + tid];
    for (int i = tid; i < Hc * Kc / 4; i += 256)
        *(float4*)&k2s[i * 4] = *(const float4*)(k2g + i * 4);

    v4f D[2][8], S[2][8];
#pragma unroll
    for (int s = 0; s < 2; s++)
#pragma unroll
        for (int ct = 0; ct < 8; ct++) {
            D[s][ct] = (v4f){0.f, 0.f, 0.f, 0.f};
            S[s][ct] = (v4f){0.f, 0.f, 0.f, 0.f};
        }

    const unsigned short* kwbase = Kp + (size_t)L * 8;
    v8s Bc0[8], Bn[8];
    {
        const unsigned short* p0 = kwbase + (size_t)(wv * 64) * 512;
#pragma unroll
        for (int ct = 0; ct < 8; ct++) Bc0[ct] = *(const v8s*)(p0 + ct * 512);
    }

    lds_barrier();   // q2s/msh/k2s visible; global loads stay in flight

    float q2r[2][4], mrow[2][4];
#pragma unroll
    for (int s = 0; s < 2; s++)
#pragma unroll
        for (int r = 0; r < 4; r++) {
            q2r[s][r] = q2s[s * 16 + qd * 4 + r];
            mrow[s][r] = msh[s * 16 + qd * 4 + r];
        }

#define KSTEP(kk, CUR, NXT)                                                        \
    do {                                                                           \
        int hn = h * 8 + (kk) + 1;                                                 \
        int hh = (hn >> 3) & 7, kn = hn & 7;                                       \
        const unsigned short* pb =                                                 \
            kwbase + (size_t)(((hh * 4 + wv) * 64 + kn * 8)) * 512;                \
        _Pragma("unroll") for (int ct = 0; ct < 8; ct++)                           \
            NXT[ct] = *(const v8s*)(pb + ct * 512);                                \
        _Pragma("unroll") for (int ct = 0; ct < 8; ct++)                           \
            D[0][ct] = __builtin_amdgcn_mfma_f32_16x16x32_bf16(A[0][kk], CUR[ct],  \
                                                               D[0][ct], 0, 0, 0);\
        _Pragma("unroll") for (int ct = 0; ct < 8; ct++)                           \
            D[1][ct] = __builtin_amdgcn_mfma_f32_16x16x32_bf16(A[1][kk], CUR[ct],  \
                                                               D[1][ct], 0, 0, 0);\
    } while (0)

    for (int h = 0; h < Hc; ++h) {
        KSTEP(0, Bc0, Bn); KSTEP(1, Bn, Bc0);
        KSTEP(2, Bc0, Bn); KSTEP(3, Bn, Bc0);
        KSTEP(4, Bc0, Bn); KSTEP(5, Bn, Bc0);
        KSTEP(6, Bc0, Bn); KSTEP(7, Bn, Bc0);

        float rs[2][4] = {{0.f, 0.f, 0.f, 0.f}, {0.f, 0.f, 0.f, 0.f}};
#pragma unroll
        for (int ct = 0; ct < 8; ct++) {
            float k2v = k2s[h * Kc + wv * 128 + ct * 16 + li];
#pragma unroll
            for (int s = 0; s < 2; s++)
#pragma unroll
                for (int r = 0; r < 4; r++) {
                    float d2 = fmaxf(q2r[s][r] + k2v - 2.f * D[s][ct][r], 0.f) * mrow[s][r];
                    float t = __builtin_amdgcn_rcpf(1.f + d2);
                    D[s][ct][r] = t;
                    rs[s][r] += t;
                }
        }
#pragma unroll
        for (int s = 0; s < 2; s++)
#pragma unroll
            for (int r = 0; r < 4; r++) {
                rs[s][r] += __shfl_xor(rs[s][r], 1, 16);
                rs[s][r] += __shfl_xor(rs[s][r], 2, 16);
                rs[s][r] += __shfl_xor(rs[s][r], 4, 16);
                rs[s][r] += __shfl_xor(rs[s][r], 8, 16);
            }
        if (li == 0) {
#pragma unroll
            for (int s = 0; s < 2; s++)
#pragma unroll
                for (int r = 0; r < 4; r++) redb[h][wv][s * 16 + qd * 4 + r] = rs[s][r];
        }
        lds_barrier();   // slot h never reused -> single light barrier per head
        float wh = conv_w[h];
        float sc[2][4];
#pragma unroll
        for (int s = 0; s < 2; s++)
#pragma unroll
            for (int r = 0; r < 4; r++) {
                int rw = s * 16 + qd * 4 + r;
                float tot = redb[h][0][rw] + redb[h][1][rw] + redb[h][2][rw] + redb[h][3][rw];
                sc[s][r] = wh * __builtin_amdgcn_rcpf(tot);
            }
#pragma unroll
        for (int s = 0; s < 2; s++)
#pragma unroll
            for (int ct = 0; ct < 8; ct++)
#pragma unroll
                for (int r = 0; r < 4; r++) {
                    S[s][ct][r] += sc[s][r] * D[s][ct][r];
                    D[s][ct][r] = 0.f;
                }
    }
#undef KSTEP

    // ---- softmax over 512 cols (light barriers) ----
    float mx[2][4] = {{-1e30f, -1e30f, -1e30f, -1e30f}, {-1e30f, -1e30f, -1e30f, -1e30f}};
#pragma unroll
    for (int s = 0; s < 2; s++)
#pragma unroll
        for (int ct = 0; ct < 8; ct++)
#pragma unroll
            for (int r = 0; r < 4; r++) mx[s][r] = fmaxf(mx[s][r], S[s][ct][r]);
#pragma unroll
    for (int s = 0; s < 2; s++)
#pragma unroll
        for (int r = 0; r < 4; r++) {
            mx[s][r] = fmaxf(mx[s][r], __shfl_xor(mx[s][r], 1, 16));
            mx[s][r] = fmaxf(mx[s][r], __shfl_xor(mx[s][r], 2, 16));
            mx[s][r] = fmaxf(mx[s][r], __shfl_xor(mx[s][r], 4, 16));
            mx[s][r] = fmaxf(mx[s][r], __shfl_xor(mx[s][r], 8, 16));
        }
    if (li == 0) {
#pragma unroll
        for (int s = 0; s < 2; s++)
#pragma unroll
            for (int r = 0; r < 4; r++) mslot[wv][s * 16 + qd * 4 + r] = mx[s][r];
    }
    lds_barrier();
#pragma unroll
    for (int s = 0; s < 2; s++)
#pragma unroll
        for (int r = 0; r < 4; r++) {
            int rw = s * 16 + qd * 4 + r;
            mx[s][r] = fmaxf(fmaxf(mslot[0][rw], mslot[1][rw]),
                             fmaxf(mslot[2][rw], mslot[3][rw]));
        }
    float es[2][4] = {{0.f, 0.f, 0.f, 0.f}, {0.f, 0.f, 0.f, 0.f}};
#pragma unroll
    for (int s = 0; s < 2; s++)
#pragma unroll
        for (int ct = 0; ct < 8; ct++)
#pragma unroll
            for (int r = 0; r < 4; r++) {
                float e = __expf(S[s][ct][r] - mx[s][r]);
                S[s][ct][r] = e;
                es[s][r] += e;
            }
#pragma unroll
    for (int s = 0; s < 2; s++)
#pragma unroll
        for (int r = 0; r < 4; r++) {
            es[s][r] += __shfl_xor(es[s][r], 1, 16);
            es[s][r] += __shfl_xor(es[s][r], 2, 16);
            es[s][r] += __shfl_xor(es[s][r], 4, 16);
            es[s][r] += __shfl_xor(es[s][r], 8, 16);
        }
    if (li == 0) {
#pragma unroll
        for (int s = 0; s < 2; s++)
#pragma unroll
            for (int r = 0; r < 4; r++) eslot[wv][s * 16 + qd * 4 + r] = es[s][r];
    }
    lds_barrier();
    float inv[2][4];
#pragma unroll
    for (int s = 0; s < 2; s++)
#pragma unroll
        for (int r = 0; r < 4; r++) {
            int rw = s * 16 + qd * 4 + r;
            float tot = eslot[0][rw] + eslot[1][rw] + eslot[2][rw] + eslot[3][rw];
            inv[s][r] = mrow[s][r] / tot;
        }
#pragma unroll
    for (int ct = 0; ct < 8; ct++) {
        int k = wv * 128 + ct * 16 + li;
        float colsum = 0.f;
#pragma unroll
        for (int s = 0; s < 2; s++) {
            float cv[4];
#pragma unroll
            for (int r = 0; r < 4; r++) {
                cv[r] = S[s][ct][r] * inv[s][r];
                C[(size_t)(gr0 + s * 16 + qd * 4 + r) * Kc + k] = cv[r];
                colsum += cv[r];
            }
            short4 t4;
            t4.x = (short)f2bf(cv[0]); t4.y = (short)f2bf(cv[1]);
            t4.z = (short)f2bf(cv[2]); t4.w = (short)f2bf(cv[3]);
            *(short4*)&Tb[k][s * 16 + qd * 4] = t4;
        }
        colsum += __shfl_xor(colsum, 16);
        colsum += __shfl_xor(colsum, 32);
        if (qd == 0) atomicAdd(&cn[b * Kc + k], colsum);
    }
    lds_barrier();
    {
        const int ns0 = (gr0 & 1023) >> 5;
#pragma unroll
        for (int kk = 0; kk < 2; kk++) {
            int k = tid * 2 + kk;
            int kt = k >> 4, klo = k & 15;
            size_t cbase = (((size_t)b * 32 + kt) * 32 + ns0) * 512;
#pragma unroll
            for (int q2i = 0; q2i < 4; q2i++) {
                short4 lo = *(short4*)&Tb[k][q2i * 8];
                short4 hi = *(short4*)&Tb[k][q2i * 8 + 4];
                short4* d = (short4*)(Ctp + cbase + (size_t)(q2i * 16 + klo) * 8);
                d[0] = lo; d[1] = hi;
            }
        }
    }
}

// ---- fused: [0,512) vmfma (V = C^T Q -> Vp bf16 packed); [512,1536) kl ----
__global__ __launch_bounds__(256) void klv_kernel(
    const unsigned short* __restrict__ Ctp, const unsigned short* __restrict__ Qbp,
    unsigned short* __restrict__ Vp, const float* __restrict__ C,
    const float* __restrict__ cn, float* __restrict__ klout) {
    __shared__ short Vt[64][76];
    __shared__ float red[4];
    int tid = threadIdx.x;
    int bx = blockIdx.x;
    if (bx < 512) {
        int w = tid >> 6, L = tid & 63;
        int qd = L >> 4, li = L & 15;
        int wr = w >> 1, wc = w & 1;
        int bb = bx >> 5;
        int rem = bx & 31;
        int ktb = rem >> 2, ftb = rem & 3;
        int KT0 = ktb * 4 + wr * 2;
        int FT0 = ftb * 4 + wc * 2;
        const unsigned short* pa0 = Ctp + (((size_t)bb * 32 + KT0) * 32) * 512 + L * 8;
        const unsigned short* pa1 = pa0 + (size_t)32 * 512;
        const unsigned short* pb0 = Qbp + (((size_t)bb * 16 + FT0) * 32) * 512 + L * 8;
        const unsigned short* pb1 = pb0 + (size_t)32 * 512;
        v4f acc[2][2];
#pragma unroll
        for (int a = 0; a < 2; a++)
#pragma unroll
            for (int c = 0; c < 2; c++) acc[a][c] = (v4f){0.f, 0.f, 0.f, 0.f};

        v8s A0 = *(const v8s*)pa0, A1 = *(const v8s*)pa1;
        v8s B0 = *(const v8s*)pb0, B1 = *(const v8s*)pb1;
        for (int ns = 0; ns < 32; ns++) {
            int nsn = (ns + 1) & 31;
            v8s A0n = *(const v8s*)(pa0 + nsn * 512);
            v8s A1n = *(const v8s*)(pa1 + nsn * 512);
            v8s B0n = *(const v8s*)(pb0 + nsn * 512);
            v8s B1n = *(const v8s*)(pb1 + nsn * 512);
            acc[0][0] = __builtin_amdgcn_mfma_f32_16x16x32_bf16(A0, B0, acc[0][0], 0, 0, 0);
            acc[0][1] = __builtin_amdgcn_mfma_f32_16x16x32_bf16(A0, B1, acc[0][1], 0, 0, 0);
            acc[1][0] = __builtin_amdgcn_mfma_f32_16x16x32_bf16(A1, B0, acc[1][0], 0, 0, 0);
            acc[1][1] = __builtin_amdgcn_mfma_f32_16x16x32_bf16(A1, B1, acc[1][1], 0, 0, 0);
            A0 = A0n; A1 = A1n; B0 = B0n; B1 = B1n;
        }
#pragma unroll
        for (int a = 0; a < 2; a++)
#pragma unroll
            for (int c = 0; c < 2; c++)
#pragma unroll
                for (int r = 0; r < 4; r++)
                    Vt[(wr * 2 + a) * 16 + qd * 4 + r][(wc * 2 + c) * 16 + li] =
                        (short)f2bf(acc[a][c][r]);
        __syncthreads();
        {
            int ci = tid >> 5, s5 = tid & 31;
            int mtl = ci >> 1, fsl = ci & 1;
            size_t mt_g = (size_t)bb * 32 + ktb * 4 + mtl;
            size_t fs_g = (size_t)ftb * 2 + fsl;
#pragma unroll
            for (int half = 0; half < 2; half++) {
                int L2 = s5 + half * 32;
                int qd2 = L2 >> 4, li2 = L2 & 15;
                short4 x0 = *(short4*)&Vt[mtl * 16 + li2][fsl * 32 + qd2 * 8];
                short4 x1 = *(short4*)&Vt[mtl * 16 + li2][fsl * 32 + qd2 * 8 + 4];
                short4* d = (short4*)(Vp + ((mt_g * 8 + fs_g) * 64 + L2) * 8);
                d[0] = x0; d[1] = x1;
            }
        }
    } else {
        int bk = bx - 512;
        int w = tid >> 6, l = tid & 63;
        float kacc = 0.f;
#pragma unroll
        for (int rr = 0; rr < 4; rr++) {
            int row = bk * 16 + w * 4 + rr;
            int b = row >> 10;
            const float* cp = C + (size_t)row * Kc + l * 8;
            const float* np = cn + b * Kc + l * 8;
            float4 c0 = *(const float4*)cp;
            float4 c1 = *(const float4*)(cp + 4);
            float4 n0 = *(const float4*)np;
            float4 n1 = *(const float4*)(np + 4);
            float p[8];
            p[0] = c0.x * c0.x / (n0.x + EPSc); p[1] = c0.y * c0.y / (n0.y + EPSc);
            p[2] = c0.z * c0.z / (n0.z + EPSc); p[3] = c0.w * c0.w / (n0.w + EPSc);
            p[4] = c1.x * c1.x / (n1.x + EPSc); p[5] = c1.y * c1.y / (n1.y + EPSc);
            p[6] = c1.z * c1.z / (n1.z + EPSc); p[7] = c1.w * c1.w / (n1.w + EPSc);
            float s = p[0] + p[1] + p[2] + p[3] + p[4] + p[5] + p[6] + p[7];
            float pn = waveReduceSum(s) + EPSc;
            float rpn = 1.0f / pn;
            float cc[8] = {c0.x, c0.y, c0.z, c0.w, c1.x, c1.y, c1.z, c1.w};
#pragma unroll
            for (int j = 0; j < 8; j++) {
                float P = p[j] * rpn;
                kacc += P * __logf((P + EPSc) / (cc[j] + EPSc));
            }
        }
        kacc = waveReduceSum(kacc);
        if (l == 0) red[w] = kacc;
        __syncthreads();
        if (tid == 0)
            atomicAdd(klout, 100.f * (red[0] + red[1] + red[2] + red[3]));
    }
}

// ---- out = leaky_relu(Vp @ Wp^T + b) via MFMA ----
__global__ __launch_bounds__(256) void ofma_kernel(
    const unsigned short* __restrict__ Vp, const unsigned short* __restrict__ Wp,
    const float* __restrict__ bias, float* __restrict__ out) {
    int tid = threadIdx.x;
    int w = tid >> 6, L = tid & 63;
    int qd = L >> 4, li = L & 15;
    int wr = w >> 1, wc = w & 1;
    int MT0 = blockIdx.x * 4 + wr * 2;
    int OT0 = blockIdx.y * 4 + wc * 2;
    const unsigned short* pa0 = Vp + ((size_t)MT0 * 8) * 512 + L * 8;
    const unsigned short* pa1 = pa0 + (size_t)8 * 512;
    const unsigned short* pb0 = Wp + ((size_t)OT0 * 8) * 512 + L * 8;
    const unsigned short* pb1 = pb0 + (size_t)8 * 512;
    v4f acc[2][2];
#pragma unroll
    for (int a = 0; a < 2; a++)
#pragma unroll
        for (int c = 0; c < 2; c++) acc[a][c] = (v4f){0.f, 0.f, 0.f, 0.f};
#pragma unroll
    for (int fs = 0; fs < 8; fs++) {
        v8s A0 = *(const v8s*)(pa0 + fs * 512);
        v8s A1 = *(const v8s*)(pa1 + fs * 512);
        v8s B0 = *(const v8s*)(pb0 + fs * 512);
        v8s B1 = *(const v8s*)(pb1 + fs * 512);
        acc[0][0] = __builtin_amdgcn_mfma_f32_16x16x32_bf16(A0, B0, acc[0][0], 0, 0, 0);
        acc[0][1] = __builtin_amdgcn_mfma_f32_16x16x32_bf16(A0, B1, acc[0][1], 0, 0, 0);
        acc[1][0] = __builtin_amdgcn_mfma_f32_16x16x32_bf16(A1, B0, acc[1][0], 0, 0, 0);
        acc[1][1] = __builtin_amdgcn_mfma_f32_16x16x32_bf16(A1, B1, acc[1][1], 0, 0, 0);
    }
#pragma unroll
    for (int c = 0; c < 2; c++) {
        float bv = bias[(OT0 + c) * 16 + li];
#pragma unroll
        for (int a = 0; a < 2; a++)
#pragma unroll
            for (int r = 0; r < 4; r++) {
                int m = (MT0 + a) * 16 + qd * 4 + r;
                int o = (OT0 + c) * 16 + li;
                float x = acc[a][c][r] + bv;
                out[(size_t)m * DOUTc + o] = x > 0.f ? x : 0.01f * x;
            }
    }
}

extern "C" void kernel_launch(void* const* d_in, const int* in_sizes, int n_in,
                              void* d_out, int out_size, void* d_ws, size_t ws_size,
                              hipStream_t stream) {
    const float* Q = (const float*)d_in[0];
    const float* keys = (const float*)d_in[1];
    const float* conv_w = (const float*)d_in[2];
    const float* lin_w = (const float*)d_in[3];
    const float* lin_b = (const float*)d_in[4];
    const int* mask = (const int*)d_in[5];

    float* out = (float*)d_out;
    float* kl = out + (size_t)Bc * Kc * DOUTc;

    float* ws = (float*)d_ws;
    float* C = ws;                                   // 8,388,608 f
    float* k2 = C + (size_t)Bc * Nc * Kc;            // 4,096 f
    float* cn = k2 + (size_t)Hc * Kc;                // 8,192 f
    unsigned short* Kp = (unsigned short*)(cn + (size_t)Bc * Kc);  // 1,048,576 us
    unsigned short* Ctp = Kp + (size_t)Hc * Kc * Fc;               // 8,388,608 us
    unsigned short* Qbp = Ctp + (size_t)Bc * Nc * Kc;              // 4,194,304 us
    unsigned short* Vp = Qbp + (size_t)Bc * Nc * Fc;               // 2,097,152 us
    unsigned short* Wp = Vp + (size_t)Bc * Kc * Fc;                // 65,536 us

    prep_all<<<3618, 256, 0, stream>>>(Q, keys, lin_w, k2, Kp, Qbp, Wp, cn, kl);
    cmfma_kernel<<<Bc * Nc / 32, 256, 0, stream>>>(Q, Kp, k2, conv_w, mask, C, cn, Ctp);
    klv_kernel<<<1536, 256, 0, stream>>>(Ctp, Qbp, Vp, C, cn, kl);
    ofma_kernel<<<dim3(Bc * Kc / 64, DOUTc / 64), 256, 0, stream>>>(Vp, Wp, lin_b, out);
}